// Round 1
// baseline (31134.906 us; speedup 1.0000x reference)
//
#include <hip/hip_runtime.h>
#include <hip/hip_cooperative_groups.h>

namespace cg = cooperative_groups;

// ---------------------------------------------------------------------------
// DecoderLSTM: B=32, N=64, F=1280, H=512, E=512, V=10000, T=80, SOS=1
// R5: dispatch-serialization fix — entire 80-step decode runs in ONE
// persistent cooperative kernel (256 blocks x 1024 thr, 1 block/CU), with
// cg grid.sync() between the 5 dependent phases per step (was 6 kernel
// launches/step = ~12us dead time each). Logits GEMM is now full-K with
// fused bias/store/argmax (drops logits_fin + partial round-trip). The
// emb-gather GEMM moved into phase 1 (amax(t-1) is barrier-separated).
// Legacy multi-kernel path retained as fallback if cooperative launch fails.
//   out layout (elements): logits[0,25.6M) h[+16384] c[+16384] attn[+163840]
// ---------------------------------------------------------------------------

#define OFF_H    25600000ull
#define OFF_C    25616384ull
#define OFF_ATTN 25632768ull

struct __align__(8) U16x4 { unsigned short x, y, z, w; };
struct F4v { float x, y, z, w; };

static __device__ __forceinline__ float bf2f(unsigned short u) {
    return __uint_as_float(((unsigned)u) << 16);
}
static __device__ __forceinline__ unsigned short f2bf(float f) {
    unsigned u = __float_as_uint(f);
    u = (u + 0x7FFFu + ((u >> 16) & 1u)) >> 16;
    return (unsigned short)u;
}
static __device__ __forceinline__ float sigf(float x) { return 1.f / (1.f + expf(-x)); }

static __device__ __forceinline__ float toF(unsigned short u) { return bf2f(u); }
static __device__ __forceinline__ float toF(float f) { return f; }
static __device__ __forceinline__ F4v ld4(const unsigned short* p) {
    U16x4 v = *(const U16x4*)p;
    return { bf2f(v.x), bf2f(v.y), bf2f(v.z), bf2f(v.w) };
}
static __device__ __forceinline__ F4v ld4(const float* p) {
    float4 v = *(const float4*)p;
    return { v.x, v.y, v.z, v.w };
}

static __device__ __forceinline__ void stw(void* o, size_t i, float v, int obf) {
    if (obf) ((unsigned short*)o)[i] = f2bf(v);
    else     ((float*)o)[i] = v;
}

// pack (value, index) so that u64 max() = argmax with first-index tie-break
static __device__ __forceinline__ unsigned long long packv(float v, int m) {
    unsigned u = __float_as_uint(v);
    u = (u & 0x80000000u) ? ~u : (u | 0x80000000u);
    return ((unsigned long long)u << 32) | (unsigned long long)(0xFFFFFFFFu - (unsigned)m);
}
static __device__ __forceinline__ unsigned long long shfl_xor_u64(unsigned long long v, int o) {
    unsigned hi = (unsigned)(v >> 32), lo = (unsigned)v;
    hi = __shfl_xor(hi, o); lo = __shfl_xor(lo, o);
    return ((unsigned long long)hi << 32) | lo;
}

// ===========================================================================
// Persistent cooperative path
// ===========================================================================

struct PArgs {
    const void* feat; const void* emb;
    const void* W1;  const void* b1;  const void* W2;  const void* b2;
    const void* Va;  const void* bVa; const void* Wh;  const void* bh;
    const void* Wc;  const void* bc;  const void* Wg;  const void* bg;
    const void* Wx;  const void* Whh; const void* blstm;
    const void* Wout; const void* bout;
    void* dout; float* ws;
};

// generic skinny GEMM unit: 128 m x 16 b, 256 threads, Kc=128 fixed.
// unit -> (kc, mb, bHalf); partial written at (kcBase+kc).
template<typename T>
static __device__ __forceinline__
void gemm_unit(int unit, int stid, const T* __restrict__ W, int ldw, int M, int KS,
               int rowBase, int kcBase, const float* __restrict__ actT,
               float* __restrict__ part)
{
    const int kc = unit % KS, rr = unit / KS;
    const int bHalf = rr & 1, mb = rr >> 1;
    const int tm = stid & 31, bg = stid >> 5;
    int m0 = mb * 128 + tm * 4;
    if (m0 > M - 4) m0 = M - 4;
    const int b0 = bHalf * 16 + bg * 2;
    const int k0 = kc * 128;
    float a00=0.f,a01=0.f,a10=0.f,a11=0.f,a20=0.f,a21=0.f,a30=0.f,a31=0.f;
    const T* wp = W + (size_t)(rowBase + k0) * ldw + m0;
    const float* ap = actT + (size_t)k0 * 32 + b0;
    #pragma unroll 8
    for (int k = 0; k < 128; ++k) {
        float2 av = *(const float2*)ap;
        F4v w = ld4(wp);
        a00 += w.x * av.x; a01 += w.x * av.y;
        a10 += w.y * av.x; a11 += w.y * av.y;
        a20 += w.z * av.x; a21 += w.z * av.y;
        a30 += w.w * av.x; a31 += w.w * av.y;
        ap += 32; wp += ldw;
    }
    float* pp = part + ((size_t)(kcBase + kc) * M + m0) * 32 + b0;
    *(float2*)(pp)      = make_float2(a00, a01);
    *(float2*)(pp + 32) = make_float2(a10, a11);
    *(float2*)(pp + 64) = make_float2(a20, a21);
    *(float2*)(pp + 96) = make_float2(a30, a31);
}

// emb-gather GEMM unit: x(t) @ Wx[0:512], act rows gathered via amax(t-1).
// unit in [0,128): kc in [0,4) -> partial slot 4+kc of gates_part.
template<typename T>
static __device__ __forceinline__
void gemm_unit_emb(int unit, int stid, const T* __restrict__ Wx,
                   const T* __restrict__ emb,
                   const unsigned long long* __restrict__ amax, int step,
                   float* __restrict__ part)
{
    const int kc = unit & 3, rr = unit >> 2;
    const int bHalf = rr & 1, mb = rr >> 1;
    const int tm = stid & 31, bg = stid >> 5;
    const int m0 = mb * 128 + tm * 4;
    const int b0 = bHalf * 16 + bg * 2;
    const int k0 = kc * 128;
    int idx0 = 1, idx1 = 1;   // SOS at t=0
    if (step > 0) {
        unsigned long long p0 = amax[(step - 1) * 32 + b0];
        unsigned long long p1 = amax[(step - 1) * 32 + b0 + 1];
        idx0 = (int)(0xFFFFFFFFu - (unsigned)(p0 & 0xFFFFFFFFull));
        idx1 = (int)(0xFFFFFFFFu - (unsigned)(p1 & 0xFFFFFFFFull));
        idx0 &= 0x3FFF; if (idx0 > 9999) idx0 = 9999;   // OOB guard
        idx1 &= 0x3FFF; if (idx1 > 9999) idx1 = 9999;
    }
    const T* e0 = emb + (size_t)idx0 * 512 + k0;
    const T* e1 = emb + (size_t)idx1 * 512 + k0;
    const T* wp = Wx + (size_t)k0 * 2048 + m0;
    float a00=0.f,a01=0.f,a10=0.f,a11=0.f,a20=0.f,a21=0.f,a30=0.f,a31=0.f;
    #pragma unroll 8
    for (int k = 0; k < 128; ++k) {
        float ax = toF(e0[k]), ay = toF(e1[k]);
        F4v w = ld4(wp);
        a00 += w.x * ax; a01 += w.x * ay;
        a10 += w.y * ax; a11 += w.y * ay;
        a20 += w.z * ax; a21 += w.z * ay;
        a30 += w.w * ax; a31 += w.w * ay;
        wp += 2048;
    }
    float* pp = part + ((size_t)(4 + kc) * 2048 + m0) * 32 + b0;
    *(float2*)(pp)      = make_float2(a00, a01);
    *(float2*)(pp + 32) = make_float2(a10, a11);
    *(float2*)(pp + 64) = make_float2(a20, a21);
    *(float2*)(pp + 96) = make_float2(a30, a31);
}

// attention: whole 1024-thread block handles one batch row
template<typename T>
static __device__ __forceinline__
void attn_block(int b, int tid, const float* __restrict__ hq_part,
                const float* __restrict__ gate_part, const float* __restrict__ encT,
                const T* __restrict__ feat, const T* __restrict__ b1v,
                const T* __restrict__ Vav, const T* __restrict__ bVav,
                const T* __restrict__ bgv, float* __restrict__ ctxgT,
                void* __restrict__ dout, int step, int obf,
                float* hqL, float* VaL, float* wL, float (*sred)[64])
{
    if (tid < 512) {
        float s = toF(b1v[tid]);
        #pragma unroll
        for (int kp = 0; kp < 4; ++kp) s += hq_part[kp * 16384 + tid * 32 + b];
        hqL[tid] = s;
        VaL[tid] = toF(Vav[tid]);
    }
    __syncthreads();
    {   // scores: 64 n's; 16 jq groups of 32 j
        const int n = tid & 63, jq = tid >> 6;
        float s = 0.f;
        const float* ep = encT + (size_t)b * 32768 + n;
        #pragma unroll 8
        for (int jj = 0; jj < 32; ++jj) {
            int j = jq * 32 + jj;
            float v = hqL[j] + ep[(size_t)j * 64];
            s += fmaxf(v, 0.f) * VaL[j];
        }
        sred[jq][n] = s;
    }
    __syncthreads();
    if (tid < 64) {
        float s = toF(bVav[0]);
        #pragma unroll
        for (int q = 0; q < 16; ++q) s += sred[q][tid];
        float mx = s;
        for (int o = 32; o; o >>= 1) mx = fmaxf(mx, __shfl_xor(mx, o));
        float e = expf(s - mx);
        float sum = e;
        for (int o = 32; o; o >>= 1) sum += __shfl_xor(sum, o);
        float w = e / sum;
        wL[tid] = w;
        stw(dout, OFF_ATTN + ((size_t)b * 80 + step) * 64 + tid, w, obf);
    }
    __syncthreads();
    const T* fp = feat + (size_t)b * 64 * 1280;
    {
        float c0 = 0.f;
        #pragma unroll 8
        for (int nn = 0; nn < 64; ++nn) c0 += wL[nn] * toF(fp[nn * 1280 + tid]);
        float g = toF(bgv[tid]);
        #pragma unroll
        for (int kp = 0; kp < 4; ++kp) g += gate_part[kp * 40960 + tid * 32 + b];
        g = 1.f / (1.f + expf(-g));
        ctxgT[tid * 32 + b] = c0 * g;
    }
    if (tid < 256) {
        int f = 1024 + tid;
        float c1 = 0.f;
        #pragma unroll 8
        for (int nn = 0; nn < 64; ++nn) c1 += wL[nn] * toF(fp[nn * 1280 + f]);
        float g = toF(bgv[f]);
        #pragma unroll
        for (int kp = 0; kp < 4; ++kp) g += gate_part[kp * 40960 + f * 32 + b];
        g = 1.f / (1.f + expf(-g));
        ctxgT[f * 32 + b] = c1 * g;
    }
}

template<typename T>
static __device__ __forceinline__
void lstm_unit(int u, int stid, const float* __restrict__ gates_part,
               const T* __restrict__ blstmv, float* __restrict__ cT,
               float* __restrict__ actT_h, void* __restrict__ dout,
               int step, int obf)
{
    int g = u * 256 + stid;                   // 16384 = 512*32
    int b = g & 31, j = g >> 5;
    float gi = toF(blstmv[j]),        gf = toF(blstmv[j + 512]);
    float gg = toF(blstmv[j + 1024]), go = toF(blstmv[j + 1536]);
    #pragma unroll
    for (int kc = 0; kc < 18; ++kc) {
        const float* p = gates_part + (size_t)kc * 2048 * 32;
        gi += p[(j       ) * 32 + b];
        gf += p[(j +  512) * 32 + b];
        gg += p[(j + 1024) * 32 + b];
        go += p[(j + 1536) * 32 + b];
    }
    float c  = cT[j * 32 + b];
    float c2 = sigf(gf) * c + sigf(gi) * tanhf(gg);
    float h2 = sigf(go) * tanhf(c2);
    cT[j * 32 + b] = c2;
    actT_h[j * 32 + b] = h2;
    if (step == 79) {
        stw(dout, OFF_H + (size_t)b * 512 + j, h2, obf);
        stw(dout, OFF_C + (size_t)b * 512 + j, c2, obf);
    }
}

// logits: full-K (K=512) GEMM with fused bias + store + argmax.
// unit in [0,158): mb = u>>1 (79 tiles of 128 m, tail clamped), bHalf = u&1.
template<typename T>
static __device__ __forceinline__
void logits_unit(int u, int stid, const T* __restrict__ Wout,
                 const float* __restrict__ actT, const T* __restrict__ bout,
                 void* __restrict__ dout, unsigned long long* __restrict__ amax,
                 int step, int obf)
{
    const int mb = u >> 1, bHalf = u & 1;
    const int tm = stid & 31, bg = stid >> 5;
    int m0 = mb * 128 + tm * 4;
    if (m0 > 9996) m0 = 9996;                 // tail dup (benign)
    const int b0 = bHalf * 16 + bg * 2;
    float a00=0.f,a01=0.f,a10=0.f,a11=0.f,a20=0.f,a21=0.f,a30=0.f,a31=0.f;
    const T* wp = Wout + m0;
    const float* ap = actT + b0;
    #pragma unroll 8
    for (int k = 0; k < 512; ++k) {
        float2 av = *(const float2*)ap;
        F4v w = ld4(wp);
        a00 += w.x * av.x; a01 += w.x * av.y;
        a10 += w.y * av.x; a11 += w.y * av.y;
        a20 += w.z * av.x; a21 += w.z * av.y;
        a30 += w.w * av.x; a31 += w.w * av.y;
        ap += 32; wp += 10000;
    }
    float l0[4], l1[4];
    {
        float bb;
        bb = toF(bout[m0 + 0]); l0[0] = a00 + bb; l1[0] = a01 + bb;
        bb = toF(bout[m0 + 1]); l0[1] = a10 + bb; l1[1] = a11 + bb;
        bb = toF(bout[m0 + 2]); l0[2] = a20 + bb; l1[2] = a21 + bb;
        bb = toF(bout[m0 + 3]); l0[3] = a30 + bb; l1[3] = a31 + bb;
    }
    size_t o0 = ((size_t)(b0    ) * 80 + step) * 10000 + m0;
    size_t o1 = ((size_t)(b0 + 1) * 80 + step) * 10000 + m0;
    if (obf) {
        U16x4 s0 = { f2bf(l0[0]), f2bf(l0[1]), f2bf(l0[2]), f2bf(l0[3]) };
        U16x4 s1 = { f2bf(l1[0]), f2bf(l1[1]), f2bf(l1[2]), f2bf(l1[3]) };
        *(U16x4*)((unsigned short*)dout + o0) = s0;
        *(U16x4*)((unsigned short*)dout + o1) = s1;
    } else {
        *(float4*)((float*)dout + o0) = make_float4(l0[0], l0[1], l0[2], l0[3]);
        *(float4*)((float*)dout + o1) = make_float4(l1[0], l1[1], l1[2], l1[3]);
    }
    unsigned long long best0 = packv(l0[0], m0), best1 = packv(l1[0], m0), p;
    #pragma unroll
    for (int i = 1; i < 4; ++i) {
        p = packv(l0[i], m0 + i); if (p > best0) best0 = p;
        p = packv(l1[i], m0 + i); if (p > best1) best1 = p;
    }
    #pragma unroll
    for (int o = 16; o; o >>= 1) {
        unsigned long long v0 = shfl_xor_u64(best0, o);
        unsigned long long v1 = shfl_xor_u64(best1, o);
        if (v0 > best0) best0 = v0;
        if (v1 > best1) best1 = v1;
    }
    if (tm == 0) {
        atomicMax(&amax[step * 32 + b0],     best0);
        atomicMax(&amax[step * 32 + b0 + 1], best1);
    }
}

// ---- init units (ported from legacy kernels) --------------------------------
template<typename T>
static __device__ __forceinline__
void mean_unit(int u, int stid, const T* __restrict__ feat, float* __restrict__ meanT)
{
    int e = u * 256 + stid;                   // 40960 = 32*1280
    int f = e % 1280, b = e / 1280;
    const T* p = feat + (size_t)b * 64 * 1280 + f;
    float s = 0.f;
    for (int nn = 0; nn < 64; ++nn) s += toF(p[(size_t)nn * 1280]);
    meanT[f * 32 + b] = s * (1.f / 64.f);
}

template<typename T>
static __device__ __forceinline__
void inithc_unit(int u, int stid, const float* __restrict__ meanT,
                 const T* __restrict__ Whv, const T* __restrict__ bhv,
                 const T* __restrict__ Wcv, const T* __restrict__ bcv,
                 float* __restrict__ actT_h, float* __restrict__ cT)
{
    int mb = u >> 2, bq = u & 3;
    int tm = stid & 31;
    int m0 = mb * 128 + tm * 4;
    int b = bq * 8 + (stid >> 5);
    bool isH = (m0 < 512);
    const T* W = isH ? Whv : Wcv;
    int mw = isH ? m0 : (m0 - 512);
    float a0=0.f,a1=0.f,a2=0.f,a3=0.f;
    const float* ap = meanT + b;
    const T* wp = W + mw;
    #pragma unroll 8
    for (int k = 0; k < 1280; ++k) {
        float av = *ap;
        F4v w = ld4(wp);
        a0 += w.x * av; a1 += w.y * av; a2 += w.z * av; a3 += w.w * av;
        ap += 32; wp += 512;
    }
    const T* bias = isH ? bhv : bcv;
    float* dst = isH ? actT_h : cT;
    dst[(mw + 0) * 32 + b] = a0 + toF(bias[mw + 0]);
    dst[(mw + 1) * 32 + b] = a1 + toF(bias[mw + 1]);
    dst[(mw + 2) * 32 + b] = a2 + toF(bias[mw + 2]);
    dst[(mw + 3) * 32 + b] = a3 + toF(bias[mw + 3]);
}

template<typename T>
static __device__ __forceinline__
void encproj_unit(int u, int stid, const T* __restrict__ feat,
                  const T* __restrict__ W2v, const T* __restrict__ b2v,
                  float* __restrict__ encT)
{
    int jb = u & 3, rowb = u >> 2;
    int tm = stid & 31, bg = stid >> 5;
    int j0 = jb * 128 + tm * 4;
    int r0 = rowb * 16 + bg * 2;
    float a00=0.f,a01=0.f,a10=0.f,a11=0.f,a20=0.f,a21=0.f,a30=0.f,a31=0.f;
    const T* f0 = feat + (size_t)r0 * 1280;
    const T* f1 = f0 + 1280;
    const T* wp = W2v + j0;
    #pragma unroll 8
    for (int k = 0; k < 1280; ++k) {
        float ax = toF(f0[k]), ay = toF(f1[k]);
        F4v w = ld4(wp);
        a00 += w.x * ax; a01 += w.x * ay;
        a10 += w.y * ax; a11 += w.y * ay;
        a20 += w.z * ax; a21 += w.z * ay;
        a30 += w.w * ax; a31 += w.w * ay;
        wp += 512;
    }
    int b = r0 >> 6, n = r0 & 63;
    float* base = encT + (size_t)b * 32768 + n;
    float bb;
    bb = toF(b2v[j0 + 0]); *(float2*)(base + (size_t)(j0 + 0) * 64) = make_float2(a00 + bb, a01 + bb);
    bb = toF(b2v[j0 + 1]); *(float2*)(base + (size_t)(j0 + 1) * 64) = make_float2(a10 + bb, a11 + bb);
    bb = toF(b2v[j0 + 2]); *(float2*)(base + (size_t)(j0 + 2) * 64) = make_float2(a20 + bb, a21 + bb);
    bb = toF(b2v[j0 + 3]); *(float2*)(base + (size_t)(j0 + 3) * 64) = make_float2(a30 + bb, a31 + bb);
}

// ---- the persistent driver --------------------------------------------------
template<typename T>
static __device__ void run_all(const PArgs A, int obf, cg::grid_group grid,
                               float* hqL, float* VaL, float* wL, float (*sred)[64])
{
    float* ws         = A.ws;
    float* encT       = ws;                    // 1,048,576
    float* meanT      = encT + 1048576;        // 40,960
    float* actT_h     = meanT + 40960;         // 16,384
    float* cT         = actT_h + 16384;        // 16,384
    float* hq_part    = cT + 16384;            // 4*512*32   = 65,536
    float* gate_part  = hq_part + 65536;       // 4*1280*32  = 163,840
    float* gates_part = gate_part + 163840;    // 18*2048*32 = 1,179,648
    float* ctxgT      = gates_part + 1179648;  // 40,960
    unsigned long long* amax = (unsigned long long*)(ctxgT + 40960);  // 80*32 u64

    const T* featp  = (const T*)A.feat;
    const T* embp   = (const T*)A.emb;
    const T* W1p    = (const T*)A.W1;
    const T* b1p    = (const T*)A.b1;
    const T* W2p    = (const T*)A.W2;
    const T* b2p    = (const T*)A.b2;
    const T* Vap    = (const T*)A.Va;
    const T* bVap   = (const T*)A.bVa;
    const T* Whp    = (const T*)A.Wh;
    const T* bhp    = (const T*)A.bh;
    const T* Wcp    = (const T*)A.Wc;
    const T* bcp    = (const T*)A.bc;
    const T* Wgp    = (const T*)A.Wg;
    const T* bgp    = (const T*)A.bg;
    const T* Wxp    = (const T*)A.Wx;
    const T* Whhp   = (const T*)A.Whh;
    const T* blstmp = (const T*)A.blstm;
    const T* Woutp  = (const T*)A.Wout;
    const T* boutp  = (const T*)A.bout;

    const int nss  = gridDim.x * 4;                            // sub-slots
    const int ss   = ((threadIdx.x >> 8) * gridDim.x) + blockIdx.x;  // sub-major spread
    const int stid = threadIdx.x & 255;

    // ---- init phase 0: amax zero, mean, encproj ----
    {
        int gt = blockIdx.x * 1024 + threadIdx.x;
        if (gt < 2560) amax[gt] = 0ull;
    }
    for (int u = ss; u < 160; u += nss) mean_unit(u, stid, featp, meanT);
    for (int u = ss; u < 512; u += nss) encproj_unit(u, stid, featp, W2p, b2p, encT);
    grid.sync();
    // ---- init phase 1: h/c from mean feature ----
    for (int u = ss; u < 32; u += nss)
        inithc_unit(u, stid, meanT, Whp, bhp, Wcp, bcp, actT_h, cT);
    grid.sync();

    for (int t = 0; t < 80; ++t) {
        // P1: hq[32] + gate[80] + Whh[128] + emb-gather[128] = 368 units
        for (int u = ss; u < 368; u += nss) {
            if (u < 32)       gemm_unit(u,       stid, W1p,  512,  512,  4, 0, 0, actT_h, hq_part);
            else if (u < 112) gemm_unit(u - 32,  stid, Wgp,  1280, 1280, 4, 0, 0, actT_h, gate_part);
            else if (u < 240) gemm_unit(u - 112, stid, Whhp, 2048, 2048, 4, 0, 0, actT_h, gates_part);
            else              gemm_unit_emb(u - 240, stid, Wxp, embp, amax, t, gates_part);
        }
        grid.sync();
        // P2: attention (32 fat block-units; persistent blocks => stable L2 reuse of feat rows)
        if (blockIdx.x < 32)
            attn_block(blockIdx.x, (int)threadIdx.x, hq_part, gate_part, encT, featp,
                       b1p, Vap, bVap, bgp, ctxgT, A.dout, t, obf, hqL, VaL, wL, sred);
        grid.sync();
        // P3: ctxg @ Wx[512:1792]  (320 units -> gates_part slots 8..17)
        for (int u = ss; u < 320; u += nss)
            gemm_unit(u, stid, Wxp, 2048, 2048, 10, 512, 8, ctxgT, gates_part);
        grid.sync();
        // P4: LSTM pointwise (64 units)
        for (int u = ss; u < 64; u += nss)
            lstm_unit(u, stid, gates_part, blstmp, cT, actT_h, A.dout, t, obf);
        grid.sync();
        // P5: logits full-K + fused bias/store/argmax (158 units)
        for (int u = ss; u < 158; u += nss)
            logits_unit(u, stid, Woutp, actT_h, boutp, A.dout, amax, t, obf);
        grid.sync();
    }
}

__global__ __launch_bounds__(1024, 4)
void decoder_persistent(PArgs A)
{
    __shared__ float hqL[512], VaL[512], wL[64];
    __shared__ float sred[16][64];
    __shared__ int s_dtf;
    if (threadIdx.x == 0) {
        const unsigned short* fU = (const unsigned short*)A.feat;
        int hits = 0;
        for (int i = 0; i < 128; ++i) {
            unsigned e = (fU[2 * i] >> 7) & 0xFF;   // even u16: mantissa-low if f32
            if (e >= 0x70 && e <= 0x8E) ++hits;
        }
        s_dtf = (hits >= 64) ? 1 : 0;               // 1 = bf16, 0 = f32
    }
    __syncthreads();
    cg::grid_group grid = cg::this_grid();
    if (s_dtf) run_all<unsigned short>(A, 1, grid, hqL, VaL, wL, sred);
    else       run_all<float>(A, 0, grid, hqL, VaL, wL, sred);
}

// ===========================================================================
// Legacy multi-kernel fallback (R4 kernel set, verbatim) — used only if the
// cooperative launch is rejected.
// ===========================================================================

struct Region {
    const void* W;
    const void* W2;
    const float* actT;
    float* part;
    int M, KS, Kc, ldw, mode, nBlocks;
};
struct SkArgs { Region r[3]; int nReg; };

__global__ __launch_bounds__(256)
void detect_init(const unsigned short* __restrict__ featU, int* __restrict__ dtf,
                 unsigned long long* __restrict__ amax)
{
    if (threadIdx.x == 0) {
        int hits = 0;
        for (int i = 0; i < 128; ++i) {
            unsigned e = (featU[2 * i] >> 7) & 0xFF;
            if (e >= 0x70 && e <= 0x8E) ++hits;
        }
        *dtf = (hits >= 64) ? 1 : 0;
    }
    for (int i = threadIdx.x; i < 2560; i += 256) amax[i] = 0ull;
}

template<typename T>
static __device__ __forceinline__
void skgemm_body(const SkArgs& a, int step, const unsigned long long* __restrict__ amax,
                 const T* __restrict__ emb)
{
    int local = blockIdx.x;
    Region R = a.r[0];
    if (a.nReg > 1 && local >= R.nBlocks) {
        local -= R.nBlocks; R = a.r[1];
        if (a.nReg > 2 && local >= R.nBlocks) { local -= R.nBlocks; R = a.r[2]; }
    }
    const int kc    = local % R.KS;
    const int rr    = local / R.KS;
    const int bHalf = rr & 1;
    const int mb    = rr >> 1;
    const int tid = threadIdx.x;
    const int tm = tid & 31, bg = tid >> 5;
    int m0 = mb * 128 + tm * 4;
    if (m0 > R.M - 4) m0 = R.M - 4;
    const int b0 = bHalf * 16 + bg * 2;
    const int k0 = kc * R.Kc;
    const int rowOff = (R.mode == 3) ? 512 : 0;

    float a00=0.f,a01=0.f,a10=0.f,a11=0.f,a20=0.f,a21=0.f,a30=0.f,a31=0.f;

    const bool gather = (R.mode == 1) && (k0 >= 512);
    const T* wp = (gather ? ((const T*)R.W2 + (size_t)(k0 - 512) * R.ldw)
                          : ((const T*)R.W  + (size_t)(k0 + rowOff) * R.ldw)) + m0;
    if (!gather) {
        const float* ap = R.actT + (size_t)k0 * 32 + b0;
        #pragma unroll 8
        for (int k = 0; k < R.Kc; ++k) {
            float2 av = *(const float2*)ap;
            F4v w = ld4(wp);
            a00 += w.x * av.x; a01 += w.x * av.y;
            a10 += w.y * av.x; a11 += w.y * av.y;
            a20 += w.z * av.x; a21 += w.z * av.y;
            a30 += w.w * av.x; a31 += w.w * av.y;
            ap += 32; wp += R.ldw;
        }
    } else {
        int idx0 = 1, idx1 = 1;
        if (step > 0) {
            unsigned long long p0 = amax[(step - 1) * 32 + b0];
            unsigned long long p1 = amax[(step - 1) * 32 + b0 + 1];
            idx0 = (int)(0xFFFFFFFFu - (unsigned)(p0 & 0xFFFFFFFFull));
            idx1 = (int)(0xFFFFFFFFu - (unsigned)(p1 & 0xFFFFFFFFull));
            idx0 &= 0x3FFF; if (idx0 > 9999) idx0 = 9999;
            idx1 &= 0x3FFF; if (idx1 > 9999) idx1 = 9999;
        }
        const T* e0 = emb + (size_t)idx0 * 512 + (k0 - 512);
        const T* e1 = emb + (size_t)idx1 * 512 + (k0 - 512);
        #pragma unroll 8
        for (int k = 0; k < R.Kc; ++k) {
            float ax = toF(e0[k]), ay = toF(e1[k]);
            F4v w = ld4(wp);
            a00 += w.x * ax; a01 += w.x * ay;
            a10 += w.y * ax; a11 += w.y * ay;
            a20 += w.z * ax; a21 += w.z * ay;
            a30 += w.w * ax; a31 += w.w * ay;
            wp += R.ldw;
        }
    }
    float* pp = R.part + ((size_t)kc * R.M + m0) * 32 + b0;
    *(float2*)(pp)      = make_float2(a00, a01);
    *(float2*)(pp + 32) = make_float2(a10, a11);
    *(float2*)(pp + 64) = make_float2(a20, a21);
    *(float2*)(pp + 96) = make_float2(a30, a31);
}

__global__ __launch_bounds__(256)
void skgemm(SkArgs a, int step, const unsigned long long* __restrict__ amax,
            const void* __restrict__ emb, const int* __restrict__ dtf)
{
    if (*dtf) skgemm_body<unsigned short>(a, step, amax, (const unsigned short*)emb);
    else      skgemm_body<float>(a, step, amax, (const float*)emb);
}

template<typename T>
static __device__ __forceinline__
void attn_body(const float* __restrict__ hq_part, const float* __restrict__ gate_part,
               const float* __restrict__ encT, const T* __restrict__ feat,
               const T* __restrict__ b1, const T* __restrict__ Va,
               const T* __restrict__ bVa, const T* __restrict__ bg_,
               float* __restrict__ ctxgT, void* __restrict__ dout, int step, int obf)
{
    __shared__ float hqL[512], VaL[512], wL[64], sred[16][64];
    const int b = blockIdx.x, tid = threadIdx.x;
    if (tid < 512) {
        float s = toF(b1[tid]);
        #pragma unroll
        for (int kp = 0; kp < 4; ++kp) s += hq_part[kp * 16384 + tid * 32 + b];
        hqL[tid] = s;
        VaL[tid] = toF(Va[tid]);
    }
    __syncthreads();
    {
        const int n = tid & 63, jq = tid >> 6;
        float s = 0.f;
        const float* ep = encT + (size_t)b * 32768 + n;
        #pragma unroll 8
        for (int jj = 0; jj < 32; ++jj) {
            int j = jq * 32 + jj;
            float v = hqL[j] + ep[(size_t)j * 64];
            s += fmaxf(v, 0.f) * VaL[j];
        }
        sred[jq][n] = s;
    }
    __syncthreads();
    if (tid < 64) {
        float s = toF(bVa[0]);
        #pragma unroll
        for (int q = 0; q < 16; ++q) s += sred[q][tid];
        float mx = s;
        for (int o = 32; o; o >>= 1) mx = fmaxf(mx, __shfl_xor(mx, o));
        float e = expf(s - mx);
        float sum = e;
        for (int o = 32; o; o >>= 1) sum += __shfl_xor(sum, o);
        float w = e / sum;
        wL[tid] = w;
        stw(dout, OFF_ATTN + ((size_t)b * 80 + step) * 64 + tid, w, obf);
    }
    __syncthreads();
    const T* fp = feat + (size_t)b * 64 * 1280;
    {
        float c0 = 0.f;
        #pragma unroll 8
        for (int nn = 0; nn < 64; ++nn) c0 += wL[nn] * toF(fp[nn * 1280 + tid]);
        float g = toF(bg_[tid]);
        #pragma unroll
        for (int kp = 0; kp < 4; ++kp) g += gate_part[kp * 40960 + tid * 32 + b];
        g = 1.f / (1.f + expf(-g));
        ctxgT[tid * 32 + b] = c0 * g;
    }
    if (tid < 256) {
        int f = 1024 + tid;
        float c1 = 0.f;
        #pragma unroll 8
        for (int nn = 0; nn < 64; ++nn) c1 += wL[nn] * toF(fp[nn * 1280 + f]);
        float g = toF(bg_[f]);
        #pragma unroll
        for (int kp = 0; kp < 4; ++kp) g += gate_part[kp * 40960 + f * 32 + b];
        g = 1.f / (1.f + expf(-g));
        ctxgT[f * 32 + b] = c1 * g;
    }
}

__global__ __launch_bounds__(1024)
void attn_kernel(const float* hq_part, const float* gate_part, const float* encT,
                 const void* feat, const void* b1, const void* Va, const void* bVa,
                 const void* bg_, float* ctxgT, void* dout, int step,
                 const int* __restrict__ dtf)
{
    int f = *dtf;
    if (f) attn_body<unsigned short>(hq_part, gate_part, encT,
               (const unsigned short*)feat, (const unsigned short*)b1,
               (const unsigned short*)Va, (const unsigned short*)bVa,
               (const unsigned short*)bg_, ctxgT, dout, step, f);
    else   attn_body<float>(hq_part, gate_part, encT,
               (const float*)feat, (const float*)b1, (const float*)Va,
               (const float*)bVa, (const float*)bg_, ctxgT, dout, step, f);
}

template<typename T>
static __device__ __forceinline__
void lstm_body(const float* __restrict__ gates_part, const T* __restrict__ blstm,
               float* __restrict__ cT, float* __restrict__ actT_h,
               void* __restrict__ dout, int step, int obf)
{
    int g = blockIdx.x * 256 + threadIdx.x;
    int b = g & 31, j = g >> 5;
    float gi = toF(blstm[j]),        gf = toF(blstm[j + 512]);
    float gg = toF(blstm[j + 1024]), go = toF(blstm[j + 1536]);
    #pragma unroll
    for (int kc = 0; kc < 18; ++kc) {
        const float* p = gates_part + (size_t)kc * 2048 * 32;
        gi += p[(j       ) * 32 + b];
        gf += p[(j +  512) * 32 + b];
        gg += p[(j + 1024) * 32 + b];
        go += p[(j + 1536) * 32 + b];
    }
    float c  = cT[j * 32 + b];
    float c2 = sigf(gf) * c + sigf(gi) * tanhf(gg);
    float h2 = sigf(go) * tanhf(c2);
    cT[j * 32 + b] = c2;
    actT_h[j * 32 + b] = h2;
    if (step == 79) {
        stw(dout, OFF_H + (size_t)b * 512 + j, h2, obf);
        stw(dout, OFF_C + (size_t)b * 512 + j, c2, obf);
    }
}

__global__ __launch_bounds__(256)
void lstm_pw(const float* gates_part, const void* blstm, float* cT, float* actT_h,
             void* dout, int step, const int* __restrict__ dtf)
{
    int f = *dtf;
    if (f) lstm_body<unsigned short>(gates_part, (const unsigned short*)blstm,
                                     cT, actT_h, dout, step, f);
    else   lstm_body<float>(gates_part, (const float*)blstm, cT, actT_h, dout, step, f);
}

template<typename T>
static __device__ __forceinline__
void logfin_body(const float* __restrict__ part, const T* __restrict__ bout,
                 void* __restrict__ dout, unsigned long long* __restrict__ amax,
                 int step, int obf)
{
    const int mb = blockIdx.x >> 1, bHalf = blockIdx.x & 1;
    const int tid = threadIdx.x, tm = tid & 31, bg = tid >> 5;
    int m0 = mb * 128 + tm * 4;
    if (m0 > 9996) m0 = 9996;
    const int b0 = bHalf * 16 + bg * 2;

    float l0[4], l1[4];
    #pragma unroll
    for (int i = 0; i < 4; ++i) { float bb = toF(bout[m0 + i]); l0[i] = bb; l1[i] = bb; }
    #pragma unroll
    for (int kc = 0; kc < 4; ++kc) {
        const float* p = part + ((size_t)kc * 10000 + m0) * 32 + b0;
        #pragma unroll
        for (int i = 0; i < 4; ++i) { l0[i] += p[i * 32]; l1[i] += p[i * 32 + 1]; }
    }
    size_t o0 = ((size_t)(b0    ) * 80 + step) * 10000 + m0;
    size_t o1 = ((size_t)(b0 + 1) * 80 + step) * 10000 + m0;
    if (obf) {
        U16x4 s0 = { f2bf(l0[0]), f2bf(l0[1]), f2bf(l0[2]), f2bf(l0[3]) };
        U16x4 s1 = { f2bf(l1[0]), f2bf(l1[1]), f2bf(l1[2]), f2bf(l1[3]) };
        *(U16x4*)((unsigned short*)dout + o0) = s0;
        *(U16x4*)((unsigned short*)dout + o1) = s1;
    } else {
        *(float4*)((float*)dout + o0) = make_float4(l0[0], l0[1], l0[2], l0[3]);
        *(float4*)((float*)dout + o1) = make_float4(l1[0], l1[1], l1[2], l1[3]);
    }
    unsigned long long best0 = packv(l0[0], m0), best1 = packv(l1[0], m0), p;
    #pragma unroll
    for (int i = 1; i < 4; ++i) {
        p = packv(l0[i], m0 + i); if (p > best0) best0 = p;
        p = packv(l1[i], m0 + i); if (p > best1) best1 = p;
    }
    #pragma unroll
    for (int o = 16; o; o >>= 1) {
        unsigned long long v0 = shfl_xor_u64(best0, o);
        unsigned long long v1 = shfl_xor_u64(best1, o);
        if (v0 > best0) best0 = v0;
        if (v1 > best1) best1 = v1;
    }
    if (tm == 0) {
        atomicMax(&amax[step * 32 + b0],     best0);
        atomicMax(&amax[step * 32 + b0 + 1], best1);
    }
}

__global__ __launch_bounds__(256)
void logits_fin(const float* part, const void* bout, void* dout,
                unsigned long long* amax, int step, const int* __restrict__ dtf)
{
    int f = *dtf;
    if (f) logfin_body<unsigned short>(part, (const unsigned short*)bout, dout, amax, step, f);
    else   logfin_body<float>(part, (const float*)bout, dout, amax, step, f);
}

template<typename T>
static __device__ __forceinline__
void mean_body(const T* __restrict__ feat, float* __restrict__ meanT)
{
    int e = blockIdx.x * 256 + threadIdx.x;
    int f = e % 1280, b = e / 1280;
    const T* p = feat + (size_t)b * 64 * 1280 + f;
    float s = 0.f;
    for (int nn = 0; nn < 64; ++nn) s += toF(p[(size_t)nn * 1280]);
    meanT[f * 32 + b] = s * (1.f / 64.f);
}
__global__ __launch_bounds__(256)
void init_mean(const void* feat, float* meanT, const int* __restrict__ dtf)
{
    if (*dtf) mean_body<unsigned short>((const unsigned short*)feat, meanT);
    else      mean_body<float>((const float*)feat, meanT);
}

template<typename T>
static __device__ __forceinline__
void inithc_body(const float* __restrict__ meanT, const T* __restrict__ Wh,
                 const T* __restrict__ bh, const T* __restrict__ Wc,
                 const T* __restrict__ bc, float* __restrict__ actT_h, float* __restrict__ cT)
{
    int mb = blockIdx.x >> 2, bq = blockIdx.x & 3;
    int tid = threadIdx.x, tm = tid & 31;
    int m0 = mb * 128 + tm * 4;
    int b = bq * 8 + (tid >> 5);
    bool isH = (m0 < 512);
    const T* W = isH ? Wh : Wc;
    int mw = isH ? m0 : (m0 - 512);
    float a0=0.f,a1=0.f,a2=0.f,a3=0.f;
    const float* ap = meanT + b;
    const T* wp = W + mw;
    #pragma unroll 8
    for (int k = 0; k < 1280; ++k) {
        float av = *ap;
        F4v w = ld4(wp);
        a0 += w.x * av; a1 += w.y * av; a2 += w.z * av; a3 += w.w * av;
        ap += 32; wp += 512;
    }
    const T* bias = isH ? bh : bc;
    float* dst = isH ? actT_h : cT;
    dst[(mw + 0) * 32 + b] = a0 + toF(bias[mw + 0]);
    dst[(mw + 1) * 32 + b] = a1 + toF(bias[mw + 1]);
    dst[(mw + 2) * 32 + b] = a2 + toF(bias[mw + 2]);
    dst[(mw + 3) * 32 + b] = a3 + toF(bias[mw + 3]);
}
__global__ __launch_bounds__(256)
void init_hc(const float* meanT, const void* Wh, const void* bh, const void* Wc,
             const void* bc, float* actT_h, float* cT, const int* __restrict__ dtf)
{
    if (*dtf) inithc_body<unsigned short>(meanT, (const unsigned short*)Wh,
                  (const unsigned short*)bh, (const unsigned short*)Wc,
                  (const unsigned short*)bc, actT_h, cT);
    else      inithc_body<float>(meanT, (const float*)Wh, (const float*)bh,
                  (const float*)Wc, (const float*)bc, actT_h, cT);
}

template<typename T>
static __device__ __forceinline__
void encproj_body(const T* __restrict__ feat, const T* __restrict__ W2,
                  const T* __restrict__ b2, float* __restrict__ encT)
{
    int jb = blockIdx.x & 3, rowb = blockIdx.x >> 2;
    int tid = threadIdx.x, tm = tid & 31, bg = tid >> 5;
    int j0 = jb * 128 + tm * 4;
    int r0 = rowb * 16 + bg * 2;
    float a00=0.f,a01=0.f,a10=0.f,a11=0.f,a20=0.f,a21=0.f,a30=0.f,a31=0.f;
    const T* f0 = feat + (size_t)r0 * 1280;
    const T* f1 = f0 + 1280;
    const T* wp = W2 + j0;
    #pragma unroll 8
    for (int k = 0; k < 1280; ++k) {
        float ax = toF(f0[k]), ay = toF(f1[k]);
        F4v w = ld4(wp);
        a00 += w.x * ax; a01 += w.x * ay;
        a10 += w.y * ax; a11 += w.y * ay;
        a20 += w.z * ax; a21 += w.z * ay;
        a30 += w.w * ax; a31 += w.w * ay;
        wp += 512;
    }
    int b = r0 >> 6, n = r0 & 63;
    float* base = encT + (size_t)b * 32768 + n;
    float bb;
    bb = toF(b2[j0 + 0]); *(float2*)(base + (size_t)(j0 + 0) * 64) = make_float2(a00 + bb, a01 + bb);
    bb = toF(b2[j0 + 1]); *(float2*)(base + (size_t)(j0 + 1) * 64) = make_float2(a10 + bb, a11 + bb);
    bb = toF(b2[j0 + 2]); *(float2*)(base + (size_t)(j0 + 2) * 64) = make_float2(a20 + bb, a21 + bb);
    bb = toF(b2[j0 + 3]); *(float2*)(base + (size_t)(j0 + 3) * 64) = make_float2(a30 + bb, a31 + bb);
}
__global__ __launch_bounds__(256)
void encproj(const void* feat, const void* W2, const void* b2, float* encT,
             const int* __restrict__ dtf)
{
    if (*dtf) encproj_body<unsigned short>((const unsigned short*)feat,
                  (const unsigned short*)W2, (const unsigned short*)b2, encT);
    else      encproj_body<float>((const float*)feat, (const float*)W2,
                  (const float*)b2, encT);
}

static void launch_legacy(void* const* d_in, void* d_out, void* d_ws, hipStream_t stream)
{
    const void* feat  = d_in[0];
    const void* emb   = d_in[3];
    const void* W1    = d_in[4];
    const void* b1    = d_in[5];
    const void* W2    = d_in[6];
    const void* b2    = d_in[7];
    const void* Va    = d_in[8];
    const void* bVa   = d_in[9];
    const void* Wh    = d_in[10];
    const void* bh    = d_in[11];
    const void* Wc    = d_in[12];
    const void* bc    = d_in[13];
    const void* Wg    = d_in[14];
    const void* bg    = d_in[15];
    const void* Wx    = d_in[16];
    const void* Whh   = d_in[17];
    const void* blstm = d_in[18];
    const void* Wout  = d_in[19];
    const void* bout  = d_in[20];

    float* ws         = (float*)d_ws;
    float* encT       = ws;
    float* meanT      = encT + 1048576;
    float* actT_h     = meanT + 40960;
    float* cT         = actT_h + 16384;
    float* hq_part    = cT + 16384;
    float* gate_part  = hq_part + 65536;
    float* gates_part = gate_part + 163840;
    float* ctxgT      = gates_part + 1179648;
    unsigned long long* amax = (unsigned long long*)(ctxgT + 40960);
    int* dtf          = (int*)(amax + 2560);
    float* k4part     = hq_part;

    detect_init<<<1, 256, 0, stream>>>((const unsigned short*)feat, dtf, amax);
    init_mean<<<160, 256, 0, stream>>>(feat, meanT, dtf);
    init_hc  <<<32, 256, 0, stream>>>(meanT, Wh, bh, Wc, bc, actT_h, cT, dtf);
    encproj  <<<512, 256, 0, stream>>>(feat, W2, b2, encT, dtf);

    SkArgs k1{};
    k1.r[0] = { W1,  nullptr, actT_h, hq_part,    512, 4, 128,  512, 0,  32 };
    k1.r[1] = { Wg,  nullptr, actT_h, gate_part, 1280, 4, 128, 1280, 0,  80 };
    k1.r[2] = { Whh, Wx,      actT_h, gates_part,2048, 8, 128, 2048, 1, 256 };
    k1.nReg = 3;
    SkArgs k3{};
    k3.r[0] = { Wx, nullptr, ctxgT,
                gates_part + (size_t)8 * 2048 * 32, 2048, 10, 128, 2048, 3, 320 };
    k3.nReg = 1;
    SkArgs k4{};
    k4.r[0] = { Wout, nullptr, actT_h, k4part, 10000, 4, 128, 10000, 0, 632 };
    k4.nReg = 1;

    for (int t = 0; t < 80; ++t) {
        skgemm     <<<368, 256,  0, stream>>>(k1, t, amax, emb, dtf);
        attn_kernel<<<32,  1024, 0, stream>>>(hq_part, gate_part, encT, feat,
                                              b1, Va, bVa, bg, ctxgT, d_out, t, dtf);
        skgemm     <<<320, 256,  0, stream>>>(k3, t, amax, emb, dtf);
        lstm_pw    <<<64,  256,  0, stream>>>(gates_part, blstm, cT, actT_h, d_out, t, dtf);
        skgemm     <<<632, 256,  0, stream>>>(k4, t, amax, emb, dtf);
        logits_fin <<<158, 256,  0, stream>>>(k4part, bout, d_out, amax, t, dtf);
    }
}

// ---------------------------------------------------------------------------
extern "C" void kernel_launch(void* const* d_in, const int* in_sizes, int n_in,
                              void* d_out, int out_size, void* d_ws, size_t ws_size,
                              hipStream_t stream)
{
    (void)in_sizes; (void)n_in; (void)out_size; (void)ws_size;

    PArgs A;
    A.feat = d_in[0];  A.emb  = d_in[3];
    A.W1   = d_in[4];  A.b1   = d_in[5];
    A.W2   = d_in[6];  A.b2   = d_in[7];
    A.Va   = d_in[8];  A.bVa  = d_in[9];
    A.Wh   = d_in[10]; A.bh   = d_in[11];
    A.Wc   = d_in[12]; A.bc   = d_in[13];
    A.Wg   = d_in[14]; A.bg   = d_in[15];
    A.Wx   = d_in[16]; A.Whh  = d_in[17];
    A.blstm = d_in[18];
    A.Wout = d_in[19]; A.bout = d_in[20];
    A.dout = d_out;
    A.ws   = (float*)d_ws;

    void* kargs[1] = { (void*)&A };
    hipError_t err = hipLaunchCooperativeKernel(
        (const void*)decoder_persistent, dim3(256), dim3(1024), kargs, 0, stream);
    if (err != hipSuccess) {
        (void)hipGetLastError();   // clear error state, fall back to legacy path
        launch_legacy(d_in, d_out, d_ws, stream);
    }
}

// Round 2
// 23357.210 us; speedup vs baseline: 1.3330x; 1.3330x over previous
//
#include <hip/hip_runtime.h>
#include <hip/hip_cooperative_groups.h>

namespace cg = cooperative_groups;

// ---------------------------------------------------------------------------
// DecoderLSTM: B=32, N=64, F=1280, H=512, E=512, V=10000, T=80, SOS=1
// R6: persistent cooperative kernel with CHEAP grid barriers. R5 showed
// cg::grid.sync()'s device-scope acquire invalidates L1/L2 every sync ->
// 4.75 GB/launch weight refetch at 190 GB/s (31 ms). Fix: cross-phase
// handoff data (partials/ctxg/actT_h/amax, ~6 MB/step) goes through
// __hip_atomic relaxed AGENT-scope accesses (coherent at the shared point,
// no cache invalidation); weights/feat/encT stay normally cached. Barrier =
// __syncthreads (drains vmcnt) + monotonic u64 arrive counter + spin.
// 4 barriers/step (logits(t-1) overlapped into phase A). Wave-granular
// work units; act tiles staged to per-wave LDS slabs with reg prefetch.
//   out layout (elements): logits[0,25.6M) h[+16384] c[+16384] attn[+163840]
// ---------------------------------------------------------------------------

#define OFF_H    25600000ull
#define OFF_C    25616384ull
#define OFF_ATTN 25632768ull

struct __align__(8) U16x4 { unsigned short x, y, z, w; };
struct F4v { float x, y, z, w; };

static __device__ __forceinline__ float bf2f(unsigned short u) {
    return __uint_as_float(((unsigned)u) << 16);
}
static __device__ __forceinline__ unsigned short f2bf(float f) {
    unsigned u = __float_as_uint(f);
    u = (u + 0x7FFFu + ((u >> 16) & 1u)) >> 16;
    return (unsigned short)u;
}
static __device__ __forceinline__ float sigf(float x) { return 1.f / (1.f + expf(-x)); }

static __device__ __forceinline__ float toF(unsigned short u) { return bf2f(u); }
static __device__ __forceinline__ float toF(float f) { return f; }
static __device__ __forceinline__ F4v ld4(const unsigned short* p) {
    U16x4 v = *(const U16x4*)p;
    return { bf2f(v.x), bf2f(v.y), bf2f(v.z), bf2f(v.w) };
}
static __device__ __forceinline__ F4v ld4(const float* p) {
    float4 v = *(const float4*)p;
    return { v.x, v.y, v.z, v.w };
}

static __device__ __forceinline__ void stw(void* o, size_t i, float v, int obf) {
    if (obf) ((unsigned short*)o)[i] = f2bf(v);
    else     ((float*)o)[i] = v;
}

// pack (value, index) so that u64 max() = argmax with first-index tie-break
static __device__ __forceinline__ unsigned long long packv(float v, int m) {
    unsigned u = __float_as_uint(v);
    u = (u & 0x80000000u) ? ~u : (u | 0x80000000u);
    return ((unsigned long long)u << 32) | (unsigned long long)(0xFFFFFFFFu - (unsigned)m);
}
static __device__ __forceinline__ unsigned long long shfl_xor_u64(unsigned long long v, int o) {
    unsigned hi = (unsigned)(v >> 32), lo = (unsigned)v;
    hi = __shfl_xor(hi, o); lo = __shfl_xor(lo, o);
    return ((unsigned long long)hi << 32) | lo;
}

// ---- agent-scope coherent access helpers (cross-XCD visible, no cache inv) --
static __device__ __forceinline__ float aldf(const float* p) {
    return __hip_atomic_load(p, __ATOMIC_RELAXED, __HIP_MEMORY_SCOPE_AGENT);
}
static __device__ __forceinline__ void astf(float* p, float v) {
    __hip_atomic_store(p, v, __ATOMIC_RELAXED, __HIP_MEMORY_SCOPE_AGENT);
}
static __device__ __forceinline__ unsigned long long aldu64(const unsigned long long* p) {
    return __hip_atomic_load(p, __ATOMIC_RELAXED, __HIP_MEMORY_SCOPE_AGENT);
}
static __device__ __forceinline__ void astu64(unsigned long long* p, unsigned long long v) {
    __hip_atomic_store(p, v, __ATOMIC_RELAXED, __HIP_MEMORY_SCOPE_AGENT);
}
static __device__ __forceinline__ void ast2(float* p, float a, float b) {
    union { float f[2]; unsigned long long u; } c; c.f[0] = a; c.f[1] = b;
    astu64((unsigned long long*)p, c.u);
}

// ---- cheap grid barrier: monotonic counter, no fences, no cache inv --------
// __syncthreads drains each wave's vmcnt (agent-scope stores then complete at
// the coherence point) before thread 0 signals arrival.
static __device__ __forceinline__
void gbar(unsigned long long* arrive, unsigned long long tgt)
{
    __syncthreads();
    if (threadIdx.x == 0) {
        __hip_atomic_fetch_add(arrive, 1ull, __ATOMIC_RELAXED, __HIP_MEMORY_SCOPE_AGENT);
        while (__hip_atomic_load(arrive, __ATOMIC_RELAXED, __HIP_MEMORY_SCOPE_AGENT) < tgt)
            __builtin_amdgcn_s_sleep(8);
    }
    __syncthreads();
}

// ===========================================================================
// Persistent cooperative path
// ===========================================================================

struct PArgs {
    const void* feat; const void* emb;
    const void* W1;  const void* b1;  const void* W2;  const void* b2;
    const void* Va;  const void* bVa; const void* Wh;  const void* bh;
    const void* Wc;  const void* bc;  const void* Wg;  const void* bg;
    const void* Wx;  const void* Whh; const void* blstm;
    const void* Wout; const void* bout;
    void* dout; float* ws;
};

// ---- wave-granular skinny GEMM core ----------------------------------------
// One wave computes a 128m x 4b tile over nchunk*128 k. Act (agent-coherent
// f32 [K][32]) is staged chunk-wise into the wave's 2 KB LDS slab (reg
// prefetch double-buffers the global loads under the previous chunk's MACs).
// Lane: tm=lane&31 -> m0+4*tm..+3 ; half=lane>>5 -> b pair (bq*4+half*2).
template<typename T>
static __device__ __forceinline__
void gemm_core(int lane, unsigned long long* __restrict__ slab,
               const T* __restrict__ W, int ldw,
               int m0, int bq, int k0, int nchunk,
               const float* __restrict__ actT, float* acc)
{
    const int half = (lane >> 5) & 1;
    const unsigned long long* abase = (const unsigned long long*)actT + (size_t)bq * 2;
    const int kk = (lane & 63) * 2;    // two act rows per lane within chunk
    unsigned long long r0, r1, r2, r3;
    {
        size_t kb = (size_t)(k0 + kk) * 16;
        r0 = aldu64(abase + kb);
        r1 = aldu64(abase + kb + 1);
        r2 = aldu64(abase + kb + 16);
        r3 = aldu64(abase + kb + 17);
    }
    const T* wp = W + (size_t)k0 * ldw + m0;
    for (int c = 0; c < nchunk; ++c) {
        const int lk = kk * 2;         // u64 slab index (2 per k)
        slab[lk]     = r0; slab[lk + 1] = r1;
        slab[lk + 2] = r2; slab[lk + 3] = r3;
        asm volatile("s_waitcnt lgkmcnt(0)" ::: "memory");
        if (c + 1 < nchunk) {
            size_t kb = (size_t)(k0 + (c + 1) * 128 + kk) * 16;
            r0 = aldu64(abase + kb);
            r1 = aldu64(abase + kb + 1);
            r2 = aldu64(abase + kb + 16);
            r3 = aldu64(abase + kb + 17);
        }
        #pragma unroll 8
        for (int k = 0; k < 128; ++k) {
            union { unsigned long long u; float f[2]; } av;
            av.u = slab[k * 2 + half];
            F4v w = ld4(wp);
            acc[0] += w.x * av.f[0]; acc[1] += w.x * av.f[1];
            acc[2] += w.y * av.f[0]; acc[3] += w.y * av.f[1];
            acc[4] += w.z * av.f[0]; acc[5] += w.z * av.f[1];
            acc[6] += w.w * av.f[0]; acc[7] += w.w * av.f[1];
            wp += ldw;
        }
        asm volatile("s_waitcnt lgkmcnt(0)" ::: "memory");
    }
}

static __device__ __forceinline__
void store_part(float* __restrict__ pp, const float* acc)
{
    ast2(pp,      acc[0], acc[1]);
    ast2(pp + 32, acc[2], acc[3]);
    ast2(pp + 64, acc[4], acc[5]);
    ast2(pp + 96, acc[6], acc[7]);
}

// emb-gather GEMM wave-unit: x(t) @ Wx[0:512], rows gathered via amax(t-1).
template<typename T>
static __device__ __forceinline__
void emb_unit_w(int w, int lane, const T* __restrict__ Wx, const T* __restrict__ emb,
                const unsigned long long* __restrict__ amax, int step,
                float* __restrict__ gates_part)
{
    const int kc = w & 3, rr = w >> 2;
    const int bq = rr & 7, mb = rr >> 3;
    const int tm = lane & 31;
    const int m0 = mb * 128 + tm * 4;
    const int b0 = bq * 4 + ((lane >> 5) & 1) * 2;
    const int k0 = kc * 128;
    int idx0 = 1, idx1 = 1;   // SOS at t=0
    if (step > 0) {
        unsigned long long p0 = aldu64(amax + (step - 1) * 32 + b0);
        unsigned long long p1 = aldu64(amax + (step - 1) * 32 + b0 + 1);
        idx0 = (int)(0xFFFFFFFFu - (unsigned)(p0 & 0xFFFFFFFFull));
        idx1 = (int)(0xFFFFFFFFu - (unsigned)(p1 & 0xFFFFFFFFull));
        idx0 &= 0x3FFF; if (idx0 > 9999) idx0 = 9999;   // OOB guard
        idx1 &= 0x3FFF; if (idx1 > 9999) idx1 = 9999;
    }
    const T* e0 = emb + (size_t)idx0 * 512 + k0;
    const T* e1 = emb + (size_t)idx1 * 512 + k0;
    const T* wp = Wx + (size_t)k0 * 2048 + m0;
    float a[8] = {0.f,0.f,0.f,0.f,0.f,0.f,0.f,0.f};
    #pragma unroll 8
    for (int k = 0; k < 128; ++k) {
        float ax = toF(e0[k]), ay = toF(e1[k]);
        F4v wv = ld4(wp);
        a[0] += wv.x * ax; a[1] += wv.x * ay;
        a[2] += wv.y * ax; a[3] += wv.y * ay;
        a[4] += wv.z * ax; a[5] += wv.z * ay;
        a[6] += wv.w * ax; a[7] += wv.w * ay;
        wp += 2048;
    }
    store_part(gates_part + ((size_t)(4 + kc) * 2048 + m0) * 32 + b0, a);
}

// logits wave-unit: full-K (512) GEMM + fused bias/store/argmax.
template<typename T>
static __device__ __forceinline__
void logits_unit_w(int w, int lane, unsigned long long* slab,
                   const T* __restrict__ Wout, const float* __restrict__ actT,
                   const T* __restrict__ bout, void* __restrict__ dout,
                   unsigned long long* __restrict__ amax, int step, int obf)
{
    const int bq = w & 7, mbq = w >> 3;
    const int tm = lane & 31;
    int m0 = mbq * 128 + tm * 4;
    if (m0 > 9996) m0 = 9996;                 // tail dup (benign)
    const int b0 = bq * 4 + ((lane >> 5) & 1) * 2;
    float acc[8] = {0.f,0.f,0.f,0.f,0.f,0.f,0.f,0.f};
    gemm_core(lane, slab, Wout, 10000, m0, bq, 0, 4, actT, acc);
    float l0[4], l1[4];
    {
        float bb;
        bb = toF(bout[m0 + 0]); l0[0] = acc[0] + bb; l1[0] = acc[1] + bb;
        bb = toF(bout[m0 + 1]); l0[1] = acc[2] + bb; l1[1] = acc[3] + bb;
        bb = toF(bout[m0 + 2]); l0[2] = acc[4] + bb; l1[2] = acc[5] + bb;
        bb = toF(bout[m0 + 3]); l0[3] = acc[6] + bb; l1[3] = acc[7] + bb;
    }
    size_t o0 = ((size_t)(b0    ) * 80 + step) * 10000 + m0;
    size_t o1 = ((size_t)(b0 + 1) * 80 + step) * 10000 + m0;
    if (obf) {
        U16x4 s0 = { f2bf(l0[0]), f2bf(l0[1]), f2bf(l0[2]), f2bf(l0[3]) };
        U16x4 s1 = { f2bf(l1[0]), f2bf(l1[1]), f2bf(l1[2]), f2bf(l1[3]) };
        *(U16x4*)((unsigned short*)dout + o0) = s0;
        *(U16x4*)((unsigned short*)dout + o1) = s1;
    } else {
        *(float4*)((float*)dout + o0) = make_float4(l0[0], l0[1], l0[2], l0[3]);
        *(float4*)((float*)dout + o1) = make_float4(l1[0], l1[1], l1[2], l1[3]);
    }
    unsigned long long best0 = packv(l0[0], m0), best1 = packv(l1[0], m0), p;
    #pragma unroll
    for (int i = 1; i < 4; ++i) {
        p = packv(l0[i], m0 + i); if (p > best0) best0 = p;
        p = packv(l1[i], m0 + i); if (p > best1) best1 = p;
    }
    #pragma unroll
    for (int o = 16; o; o >>= 1) {
        unsigned long long v0 = shfl_xor_u64(best0, o);
        unsigned long long v1 = shfl_xor_u64(best1, o);
        if (v0 > best0) best0 = v0;
        if (v1 > best1) best1 = v1;
    }
    if (tm == 0) {
        atomicMax(&amax[step * 32 + b0],     best0);
        atomicMax(&amax[step * 32 + b0 + 1], best1);
    }
}

// attention: whole 1024-thread block handles one batch row
template<typename T>
static __device__ __forceinline__
void attn_block(int b, int tid, const float* __restrict__ hq_part,
                const float* __restrict__ gate_part, const float* __restrict__ encT,
                const T* __restrict__ feat, const T* __restrict__ b1v,
                const T* __restrict__ Vav, const T* __restrict__ bVav,
                const T* __restrict__ bgv, float* __restrict__ ctxgT,
                void* __restrict__ dout, int step, int obf,
                float* hqL, float* VaL, float* wL, float (*sred)[64])
{
    if (tid < 512) {
        float s = toF(b1v[tid]);
        #pragma unroll
        for (int kp = 0; kp < 4; ++kp) s += aldf(hq_part + kp * 16384 + tid * 32 + b);
        hqL[tid] = s;
        VaL[tid] = toF(Vav[tid]);
    }
    __syncthreads();
    {   // scores: 64 n's; 16 jq groups of 32 j
        const int n = tid & 63, jq = tid >> 6;
        float s = 0.f;
        const float* ep = encT + (size_t)b * 32768 + n;
        #pragma unroll 8
        for (int jj = 0; jj < 32; ++jj) {
            int j = jq * 32 + jj;
            float v = hqL[j] + ep[(size_t)j * 64];
            s += fmaxf(v, 0.f) * VaL[j];
        }
        sred[jq][n] = s;
    }
    __syncthreads();
    if (tid < 64) {
        float s = toF(bVav[0]);
        #pragma unroll
        for (int q = 0; q < 16; ++q) s += sred[q][tid];
        float mx = s;
        for (int o = 32; o; o >>= 1) mx = fmaxf(mx, __shfl_xor(mx, o));
        float e = expf(s - mx);
        float sum = e;
        for (int o = 32; o; o >>= 1) sum += __shfl_xor(sum, o);
        float w = e / sum;
        wL[tid] = w;
        stw(dout, OFF_ATTN + ((size_t)b * 80 + step) * 64 + tid, w, obf);
    }
    __syncthreads();
    const T* fp = feat + (size_t)b * 64 * 1280;
    {
        float c0 = 0.f;
        #pragma unroll 8
        for (int nn = 0; nn < 64; ++nn) c0 += wL[nn] * toF(fp[nn * 1280 + tid]);
        float g = toF(bgv[tid]);
        #pragma unroll
        for (int kp = 0; kp < 4; ++kp) g += aldf(gate_part + kp * 40960 + tid * 32 + b);
        g = 1.f / (1.f + expf(-g));
        astf(ctxgT + tid * 32 + b, c0 * g);
    }
    if (tid < 256) {
        int f = 1024 + tid;
        float c1 = 0.f;
        #pragma unroll 8
        for (int nn = 0; nn < 64; ++nn) c1 += wL[nn] * toF(fp[nn * 1280 + f]);
        float g = toF(bgv[f]);
        #pragma unroll
        for (int kp = 0; kp < 4; ++kp) g += aldf(gate_part + kp * 40960 + f * 32 + b);
        g = 1.f / (1.f + expf(-g));
        astf(ctxgT + f * 32 + b, c1 * g);
    }
}

// LSTM pointwise wave-unit: 64 outputs per wave, 256 wave-units.
template<typename T>
static __device__ __forceinline__
void lstm_unit_w(int w, int lane, const float* __restrict__ gates_part,
                 const T* __restrict__ blstmv, float* __restrict__ cT,
                 float* __restrict__ actT_h, void* __restrict__ dout,
                 int step, int obf)
{
    int g = w * 64 + lane;                    // 16384 = 512*32
    int b = g & 31, j = g >> 5;
    float gi = toF(blstmv[j]),        gf = toF(blstmv[j + 512]);
    float gg = toF(blstmv[j + 1024]), go = toF(blstmv[j + 1536]);
    #pragma unroll
    for (int kc = 0; kc < 18; ++kc) {
        const float* p = gates_part + (size_t)kc * 65536;
        gi += aldf(p + (j       ) * 32 + b);
        gf += aldf(p + (j +  512) * 32 + b);
        gg += aldf(p + (j + 1024) * 32 + b);
        go += aldf(p + (j + 1536) * 32 + b);
    }
    float c  = cT[j * 32 + b];                // block-private across steps
    float c2 = sigf(gf) * c + sigf(gi) * tanhf(gg);
    float h2 = sigf(go) * tanhf(c2);
    cT[j * 32 + b] = c2;
    astf(actT_h + j * 32 + b, h2);            // cross-block next phase
    if (step == 79) {
        stw(dout, OFF_H + (size_t)b * 512 + j, h2, obf);
        stw(dout, OFF_C + (size_t)b * 512 + j, c2, obf);
    }
}

// ---- init units (sub-unit granularity; crossed via real cg.sync) -----------
template<typename T>
static __device__ __forceinline__
void mean_unit(int u, int stid, const T* __restrict__ feat, float* __restrict__ meanT)
{
    int e = u * 256 + stid;                   // 40960 = 32*1280
    int f = e % 1280, b = e / 1280;
    const T* p = feat + (size_t)b * 64 * 1280 + f;
    float s = 0.f;
    for (int nn = 0; nn < 64; ++nn) s += toF(p[(size_t)nn * 1280]);
    meanT[f * 32 + b] = s * (1.f / 64.f);
}

template<typename T>
static __device__ __forceinline__
void inithc_unit(int u, int stid, const float* __restrict__ meanT,
                 const T* __restrict__ Whv, const T* __restrict__ bhv,
                 const T* __restrict__ Wcv, const T* __restrict__ bcv,
                 float* __restrict__ actT_h, float* __restrict__ cT)
{
    int mb = u >> 2, bq = u & 3;
    int tm = stid & 31;
    int m0 = mb * 128 + tm * 4;
    int b = bq * 8 + (stid >> 5);
    bool isH = (m0 < 512);
    const T* W = isH ? Whv : Wcv;
    int mw = isH ? m0 : (m0 - 512);
    float a0=0.f,a1=0.f,a2=0.f,a3=0.f;
    const float* ap = meanT + b;
    const T* wp = W + mw;
    #pragma unroll 8
    for (int k = 0; k < 1280; ++k) {
        float av = *ap;
        F4v w = ld4(wp);
        a0 += w.x * av; a1 += w.y * av; a2 += w.z * av; a3 += w.w * av;
        ap += 32; wp += 512;
    }
    const T* bias = isH ? bhv : bcv;
    float* dst = isH ? actT_h : cT;
    dst[(mw + 0) * 32 + b] = a0 + toF(bias[mw + 0]);
    dst[(mw + 1) * 32 + b] = a1 + toF(bias[mw + 1]);
    dst[(mw + 2) * 32 + b] = a2 + toF(bias[mw + 2]);
    dst[(mw + 3) * 32 + b] = a3 + toF(bias[mw + 3]);
}

template<typename T>
static __device__ __forceinline__
void encproj_unit(int u, int stid, const T* __restrict__ feat,
                  const T* __restrict__ W2v, const T* __restrict__ b2v,
                  float* __restrict__ encT)
{
    int jb = u & 3, rowb = u >> 2;
    int tm = stid & 31, bg = stid >> 5;
    int j0 = jb * 128 + tm * 4;
    int r0 = rowb * 16 + bg * 2;
    float a00=0.f,a01=0.f,a10=0.f,a11=0.f,a20=0.f,a21=0.f,a30=0.f,a31=0.f;
    const T* f0 = feat + (size_t)r0 * 1280;
    const T* f1 = f0 + 1280;
    const T* wp = W2v + j0;
    #pragma unroll 8
    for (int k = 0; k < 1280; ++k) {
        float ax = toF(f0[k]), ay = toF(f1[k]);
        F4v w = ld4(wp);
        a00 += w.x * ax; a01 += w.x * ay;
        a10 += w.y * ax; a11 += w.y * ay;
        a20 += w.z * ax; a21 += w.z * ay;
        a30 += w.w * ax; a31 += w.w * ay;
        wp += 512;
    }
    int b = r0 >> 6, n = r0 & 63;
    float* base = encT + (size_t)b * 32768 + n;
    float bb;
    bb = toF(b2v[j0 + 0]); *(float2*)(base + (size_t)(j0 + 0) * 64) = make_float2(a00 + bb, a01 + bb);
    bb = toF(b2v[j0 + 1]); *(float2*)(base + (size_t)(j0 + 1) * 64) = make_float2(a10 + bb, a11 + bb);
    bb = toF(b2v[j0 + 2]); *(float2*)(base + (size_t)(j0 + 2) * 64) = make_float2(a20 + bb, a21 + bb);
    bb = toF(b2v[j0 + 3]); *(float2*)(base + (size_t)(j0 + 3) * 64) = make_float2(a30 + bb, a31 + bb);
}

// ---- the persistent driver --------------------------------------------------
template<typename T>
static __device__ void run_all(const PArgs A, int obf, cg::grid_group grid,
                               unsigned long long* slab,
                               float* hqL, float* VaL, float* wL, float (*sred)[64])
{
    float* ws         = A.ws;
    float* encT       = ws;                    // 1,048,576
    float* meanT      = encT + 1048576;        // 40,960
    float* actT_h     = meanT + 40960;         // 16,384
    float* cT         = actT_h + 16384;        // 16,384
    float* hq_part    = cT + 16384;            // 4*512*32   = 65,536
    float* gate_part  = hq_part + 65536;       // 4*1280*32  = 163,840
    float* gates_part = gate_part + 163840;    // 18*2048*32 = 1,179,648
    float* ctxgT      = gates_part + 1179648;  // 40,960
    unsigned long long* amax = (unsigned long long*)(ctxgT + 40960);  // 80*32 u64
    unsigned long long* arrive = amax + 2568;  // barrier counter (skip legacy dtf slot)

    const T* featp  = (const T*)A.feat;
    const T* embp   = (const T*)A.emb;
    const T* W1p    = (const T*)A.W1;
    const T* b1p    = (const T*)A.b1;
    const T* W2p    = (const T*)A.W2;
    const T* b2p    = (const T*)A.b2;
    const T* Vap    = (const T*)A.Va;
    const T* bVap   = (const T*)A.bVa;
    const T* Whp    = (const T*)A.Wh;
    const T* bhp    = (const T*)A.bh;
    const T* Wcp    = (const T*)A.Wc;
    const T* bcp    = (const T*)A.bc;
    const T* Wgp    = (const T*)A.Wg;
    const T* bgp    = (const T*)A.bg;
    const T* Wxp    = (const T*)A.Wx;
    const T* Whhp   = (const T*)A.Whh;
    const T* blstmp = (const T*)A.blstm;
    const T* Woutp  = (const T*)A.Wout;
    const T* boutp  = (const T*)A.bout;

    const int NB   = gridDim.x;                                // 256
    const int lane = threadIdx.x & 63;
    const int wvb  = threadIdx.x >> 6;                         // wave in block 0..15
    const int gw   = wvb * NB + blockIdx.x;                    // 0..4095
    const int nws  = NB * 16;
    // sub-unit mapping for init phases (256-thr units)
    const int nss  = NB * 4;
    const int ss   = (threadIdx.x >> 8) * NB + blockIdx.x;
    const int stid = threadIdx.x & 255;

    // ---- init: zero amax + arrive, mean, encproj (real grid syncs) ----
    if (blockIdx.x == 0 && threadIdx.x == 0) astu64(arrive, 0ull);
    {
        int gt = blockIdx.x * 1024 + threadIdx.x;
        if (gt < 2560) astu64(amax + gt, 0ull);
    }
    for (int u = ss; u < 160; u += nss) mean_unit(u, stid, featp, meanT);
    for (int u = ss; u < 512; u += nss) encproj_unit(u, stid, featp, W2p, b2p, encT);
    grid.sync();
    for (int u = ss; u < 32; u += nss)
        inithc_unit(u, stid, meanT, Whp, bhp, Wcp, bcp, actT_h, cT);
    grid.sync();

    unsigned long long barN = 0;
    #define GB() gbar(arrive, (++barN) * (unsigned long long)NB)

    for (int t = 0; t < 80; ++t) {
        // ---- Phase A: hq/gate/Whh (t) [960 wave-units] + logits(t-1) [632] --
        for (int w = gw; w < 960; w += nws) {
            const T* W; int ldw, M; float* part; int v;
            if (w < 128)      { v = w;       W = W1p;  ldw = 512;  M = 512;  part = hq_part; }
            else if (w < 448) { v = w - 128; W = Wgp;  ldw = 1280; M = 1280; part = gate_part; }
            else              { v = w - 448; W = Whhp; ldw = 2048; M = 2048; part = gates_part; }
            const int kc = v & 3; const int rr = v >> 2;
            const int bq = rr & 7, mb = rr >> 3;
            const int m0 = mb * 128 + (lane & 31) * 4;
            float acc[8] = {0.f,0.f,0.f,0.f,0.f,0.f,0.f,0.f};
            gemm_core(lane, slab, W, ldw, m0, bq, kc * 128, 1, actT_h, acc);
            const int b0 = bq * 4 + ((lane >> 5) & 1) * 2;
            store_part(part + ((size_t)kc * M + m0) * 32 + b0, acc);
        }
        if (t > 0)
            for (int w = gw; w < 632; w += nws)
                logits_unit_w(w, lane, slab, Woutp, actT_h, boutp, A.dout, amax, t - 1, obf);
        GB();
        // ---- Phase B: attn(t) on blocks 0..31 | emb-gather(t) on blocks >=32
        if (blockIdx.x < 32) {
            attn_block(blockIdx.x, (int)threadIdx.x, hq_part, gate_part, encT, featp,
                       b1p, Vap, bVap, bgp, ctxgT, A.dout, t, obf, hqL, VaL, wL, sred);
        } else {
            const int gwE = wvb * (NB - 32) + (blockIdx.x - 32);
            for (int w = gwE; w < 512; w += (NB - 32) * 16)
                emb_unit_w(w, lane, Wxp, embp, amax, t, gates_part);
        }
        GB();
        // ---- Phase C: ctxg @ Wx[512:1792] [1280 wave-units -> slots 8..17] --
        for (int w = gw; w < 1280; w += nws) {
            const int kc = w % 10; const int rr = w / 10;
            const int bq = rr & 7, mb = rr >> 3;
            const int m0 = mb * 128 + (lane & 31) * 4;
            float acc[8] = {0.f,0.f,0.f,0.f,0.f,0.f,0.f,0.f};
            gemm_core(lane, slab, Wxp + (size_t)512 * 2048, 2048, m0, bq, kc * 128, 1,
                      ctxgT, acc);
            const int b0 = bq * 4 + ((lane >> 5) & 1) * 2;
            store_part(gates_part + ((size_t)(8 + kc) * 2048 + m0) * 32 + b0, acc);
        }
        GB();
        // ---- Phase D: LSTM pointwise [256 wave-units] ----
        for (int w = gw; w < 256; w += nws)
            lstm_unit_w(w, lane, gates_part, blstmp, cT, actT_h, A.dout, t, obf);
        GB();
    }
    // final logits for t=79 (kernel end flushes dout)
    for (int w = gw; w < 632; w += nws)
        logits_unit_w(w, lane, slab, Woutp, actT_h, boutp, A.dout, amax, 79, obf);
    #undef GB
}

__global__ __launch_bounds__(1024, 4)
void decoder_persistent(PArgs A)
{
    __shared__ unsigned long long slabs[16][256];   // 2 KB act slab per wave
    __shared__ float hqL[512], VaL[512], wL[64];
    __shared__ float sred[16][64];
    __shared__ int s_dtf;
    if (threadIdx.x == 0) {
        const unsigned short* fU = (const unsigned short*)A.feat;
        int hits = 0;
        for (int i = 0; i < 128; ++i) {
            unsigned e = (fU[2 * i] >> 7) & 0xFF;   // even u16: mantissa-low if f32
            if (e >= 0x70 && e <= 0x8E) ++hits;
        }
        s_dtf = (hits >= 64) ? 1 : 0;               // 1 = bf16, 0 = f32
    }
    __syncthreads();
    cg::grid_group grid = cg::this_grid();
    unsigned long long* slab = &slabs[threadIdx.x >> 6][0];
    if (s_dtf) run_all<unsigned short>(A, 1, grid, slab, hqL, VaL, wL, sred);
    else       run_all<float>(A, 0, grid, slab, hqL, VaL, wL, sred);
}

// ===========================================================================
// Legacy multi-kernel fallback (R4 kernel set, verbatim) — used only if the
// cooperative launch is rejected.
// ===========================================================================

struct Region {
    const void* W;
    const void* W2;
    const float* actT;
    float* part;
    int M, KS, Kc, ldw, mode, nBlocks;
};
struct SkArgs { Region r[3]; int nReg; };

__global__ __launch_bounds__(256)
void detect_init(const unsigned short* __restrict__ featU, int* __restrict__ dtf,
                 unsigned long long* __restrict__ amax)
{
    if (threadIdx.x == 0) {
        int hits = 0;
        for (int i = 0; i < 128; ++i) {
            unsigned e = (featU[2 * i] >> 7) & 0xFF;
            if (e >= 0x70 && e <= 0x8E) ++hits;
        }
        *dtf = (hits >= 64) ? 1 : 0;
    }
    for (int i = threadIdx.x; i < 2560; i += 256) amax[i] = 0ull;
}

template<typename T>
static __device__ __forceinline__
void skgemm_body(const SkArgs& a, int step, const unsigned long long* __restrict__ amax,
                 const T* __restrict__ emb)
{
    int local = blockIdx.x;
    Region R = a.r[0];
    if (a.nReg > 1 && local >= R.nBlocks) {
        local -= R.nBlocks; R = a.r[1];
        if (a.nReg > 2 && local >= R.nBlocks) { local -= R.nBlocks; R = a.r[2]; }
    }
    const int kc    = local % R.KS;
    const int rr    = local / R.KS;
    const int bHalf = rr & 1;
    const int mb    = rr >> 1;
    const int tid = threadIdx.x;
    const int tm = tid & 31, bg = tid >> 5;
    int m0 = mb * 128 + tm * 4;
    if (m0 > R.M - 4) m0 = R.M - 4;
    const int b0 = bHalf * 16 + bg * 2;
    const int k0 = kc * R.Kc;
    const int rowOff = (R.mode == 3) ? 512 : 0;

    float a00=0.f,a01=0.f,a10=0.f,a11=0.f,a20=0.f,a21=0.f,a30=0.f,a31=0.f;

    const bool gather = (R.mode == 1) && (k0 >= 512);
    const T* wp = (gather ? ((const T*)R.W2 + (size_t)(k0 - 512) * R.ldw)
                          : ((const T*)R.W  + (size_t)(k0 + rowOff) * R.ldw)) + m0;
    if (!gather) {
        const float* ap = R.actT + (size_t)k0 * 32 + b0;
        #pragma unroll 8
        for (int k = 0; k < R.Kc; ++k) {
            float2 av = *(const float2*)ap;
            F4v w = ld4(wp);
            a00 += w.x * av.x; a01 += w.x * av.y;
            a10 += w.y * av.x; a11 += w.y * av.y;
            a20 += w.z * av.x; a21 += w.z * av.y;
            a30 += w.w * av.x; a31 += w.w * av.y;
            ap += 32; wp += R.ldw;
        }
    } else {
        int idx0 = 1, idx1 = 1;
        if (step > 0) {
            unsigned long long p0 = amax[(step - 1) * 32 + b0];
            unsigned long long p1 = amax[(step - 1) * 32 + b0 + 1];
            idx0 = (int)(0xFFFFFFFFu - (unsigned)(p0 & 0xFFFFFFFFull));
            idx1 = (int)(0xFFFFFFFFu - (unsigned)(p1 & 0xFFFFFFFFull));
            idx0 &= 0x3FFF; if (idx0 > 9999) idx0 = 9999;
            idx1 &= 0x3FFF; if (idx1 > 9999) idx1 = 9999;
        }
        const T* e0 = emb + (size_t)idx0 * 512 + (k0 - 512);
        const T* e1 = emb + (size_t)idx1 * 512 + (k0 - 512);
        #pragma unroll 8
        for (int k = 0; k < R.Kc; ++k) {
            float ax = toF(e0[k]), ay = toF(e1[k]);
            F4v w = ld4(wp);
            a00 += w.x * ax; a01 += w.x * ay;
            a10 += w.y * ax; a11 += w.y * ay;
            a20 += w.z * ax; a21 += w.z * ay;
            a30 += w.w * ax; a31 += w.w * ay;
            wp += R.ldw;
        }
    }
    float* pp = R.part + ((size_t)kc * R.M + m0) * 32 + b0;
    *(float2*)(pp)      = make_float2(a00, a01);
    *(float2*)(pp + 32) = make_float2(a10, a11);
    *(float2*)(pp + 64) = make_float2(a20, a21);
    *(float2*)(pp + 96) = make_float2(a30, a31);
}

__global__ __launch_bounds__(256)
void skgemm(SkArgs a, int step, const unsigned long long* __restrict__ amax,
            const void* __restrict__ emb, const int* __restrict__ dtf)
{
    if (*dtf) skgemm_body<unsigned short>(a, step, amax, (const unsigned short*)emb);
    else      skgemm_body<float>(a, step, amax, (const float*)emb);
}

template<typename T>
static __device__ __forceinline__
void attn_body(const float* __restrict__ hq_part, const float* __restrict__ gate_part,
               const float* __restrict__ encT, const T* __restrict__ feat,
               const T* __restrict__ b1, const T* __restrict__ Va,
               const T* __restrict__ bVa, const T* __restrict__ bg_,
               float* __restrict__ ctxgT, void* __restrict__ dout, int step, int obf)
{
    __shared__ float hqL[512], VaL[512], wL[64], sred[16][64];
    const int b = blockIdx.x, tid = threadIdx.x;
    if (tid < 512) {
        float s = toF(b1[tid]);
        #pragma unroll
        for (int kp = 0; kp < 4; ++kp) s += hq_part[kp * 16384 + tid * 32 + b];
        hqL[tid] = s;
        VaL[tid] = toF(Va[tid]);
    }
    __syncthreads();
    {
        const int n = tid & 63, jq = tid >> 6;
        float s = 0.f;
        const float* ep = encT + (size_t)b * 32768 + n;
        #pragma unroll 8
        for (int jj = 0; jj < 32; ++jj) {
            int j = jq * 32 + jj;
            float v = hqL[j] + ep[(size_t)j * 64];
            s += fmaxf(v, 0.f) * VaL[j];
        }
        sred[jq][n] = s;
    }
    __syncthreads();
    if (tid < 64) {
        float s = toF(bVa[0]);
        #pragma unroll
        for (int q = 0; q < 16; ++q) s += sred[q][tid];
        float mx = s;
        for (int o = 32; o; o >>= 1) mx = fmaxf(mx, __shfl_xor(mx, o));
        float e = expf(s - mx);
        float sum = e;
        for (int o = 32; o; o >>= 1) sum += __shfl_xor(sum, o);
        float w = e / sum;
        wL[tid] = w;
        stw(dout, OFF_ATTN + ((size_t)b * 80 + step) * 64 + tid, w, obf);
    }
    __syncthreads();
    const T* fp = feat + (size_t)b * 64 * 1280;
    {
        float c0 = 0.f;
        #pragma unroll 8
        for (int nn = 0; nn < 64; ++nn) c0 += wL[nn] * toF(fp[nn * 1280 + tid]);
        float g = toF(bg_[tid]);
        #pragma unroll
        for (int kp = 0; kp < 4; ++kp) g += gate_part[kp * 40960 + tid * 32 + b];
        g = 1.f / (1.f + expf(-g));
        ctxgT[tid * 32 + b] = c0 * g;
    }
    if (tid < 256) {
        int f = 1024 + tid;
        float c1 = 0.f;
        #pragma unroll 8
        for (int nn = 0; nn < 64; ++nn) c1 += wL[nn] * toF(fp[nn * 1280 + f]);
        float g = toF(bg_[f]);
        #pragma unroll
        for (int kp = 0; kp < 4; ++kp) g += gate_part[kp * 40960 + f * 32 + b];
        g = 1.f / (1.f + expf(-g));
        ctxgT[f * 32 + b] = c1 * g;
    }
}

__global__ __launch_bounds__(1024)
void attn_kernel(const float* hq_part, const float* gate_part, const float* encT,
                 const void* feat, const void* b1, const void* Va, const void* bVa,
                 const void* bg_, float* ctxgT, void* dout, int step,
                 const int* __restrict__ dtf)
{
    int f = *dtf;
    if (f) attn_body<unsigned short>(hq_part, gate_part, encT,
               (const unsigned short*)feat, (const unsigned short*)b1,
               (const unsigned short*)Va, (const unsigned short*)bVa,
               (const unsigned short*)bg_, ctxgT, dout, step, f);
    else   attn_body<float>(hq_part, gate_part, encT,
               (const float*)feat, (const float*)b1, (const float*)Va,
               (const float*)bVa, (const float*)bg_, ctxgT, dout, step, f);
}

template<typename T>
static __device__ __forceinline__
void lstm_body(const float* __restrict__ gates_part, const T* __restrict__ blstm,
               float* __restrict__ cT, float* __restrict__ actT_h,
               void* __restrict__ dout, int step, int obf)
{
    int g = blockIdx.x * 256 + threadIdx.x;
    int b = g & 31, j = g >> 5;
    float gi = toF(blstm[j]),        gf = toF(blstm[j + 512]);
    float gg = toF(blstm[j + 1024]), go = toF(blstm[j + 1536]);
    #pragma unroll
    for (int kc = 0; kc < 18; ++kc) {
        const float* p = gates_part + (size_t)kc * 2048 * 32;
        gi += p[(j       ) * 32 + b];
        gf += p[(j +  512) * 32 + b];
        gg += p[(j + 1024) * 32 + b];
        go += p[(j + 1536) * 32 + b];
    }
    float c  = cT[j * 32 + b];
    float c2 = sigf(gf) * c + sigf(gi) * tanhf(gg);
    float h2 = sigf(go) * tanhf(c2);
    cT[j * 32 + b] = c2;
    actT_h[j * 32 + b] = h2;
    if (step == 79) {
        stw(dout, OFF_H + (size_t)b * 512 + j, h2, obf);
        stw(dout, OFF_C + (size_t)b * 512 + j, c2, obf);
    }
}

__global__ __launch_bounds__(256)
void lstm_pw(const float* gates_part, const void* blstm, float* cT, float* actT_h,
             void* dout, int step, const int* __restrict__ dtf)
{
    int f = *dtf;
    if (f) lstm_body<unsigned short>(gates_part, (const unsigned short*)blstm,
                                     cT, actT_h, dout, step, f);
    else   lstm_body<float>(gates_part, (const float*)blstm, cT, actT_h, dout, step, f);
}

template<typename T>
static __device__ __forceinline__
void logfin_body(const float* __restrict__ part, const T* __restrict__ bout,
                 void* __restrict__ dout, unsigned long long* __restrict__ amax,
                 int step, int obf)
{
    const int mb = blockIdx.x >> 1, bHalf = blockIdx.x & 1;
    const int tid = threadIdx.x, tm = tid & 31, bg = tid >> 5;
    int m0 = mb * 128 + tm * 4;
    if (m0 > 9996) m0 = 9996;
    const int b0 = bHalf * 16 + bg * 2;

    float l0[4], l1[4];
    #pragma unroll
    for (int i = 0; i < 4; ++i) { float bb = toF(bout[m0 + i]); l0[i] = bb; l1[i] = bb; }
    #pragma unroll
    for (int kc = 0; kc < 4; ++kc) {
        const float* p = part + ((size_t)kc * 10000 + m0) * 32 + b0;
        #pragma unroll
        for (int i = 0; i < 4; ++i) { l0[i] += p[i * 32]; l1[i] += p[i * 32 + 1]; }
    }
    size_t o0 = ((size_t)(b0    ) * 80 + step) * 10000 + m0;
    size_t o1 = ((size_t)(b0 + 1) * 80 + step) * 10000 + m0;
    if (obf) {
        U16x4 s0 = { f2bf(l0[0]), f2bf(l0[1]), f2bf(l0[2]), f2bf(l0[3]) };
        U16x4 s1 = { f2bf(l1[0]), f2bf(l1[1]), f2bf(l1[2]), f2bf(l1[3]) };
        *(U16x4*)((unsigned short*)dout + o0) = s0;
        *(U16x4*)((unsigned short*)dout + o1) = s1;
    } else {
        *(float4*)((float*)dout + o0) = make_float4(l0[0], l0[1], l0[2], l0[3]);
        *(float4*)((float*)dout + o1) = make_float4(l1[0], l1[1], l1[2], l1[3]);
    }
    unsigned long long best0 = packv(l0[0], m0), best1 = packv(l1[0], m0), p;
    #pragma unroll
    for (int i = 1; i < 4; ++i) {
        p = packv(l0[i], m0 + i); if (p > best0) best0 = p;
        p = packv(l1[i], m0 + i); if (p > best1) best1 = p;
    }
    #pragma unroll
    for (int o = 16; o; o >>= 1) {
        unsigned long long v0 = shfl_xor_u64(best0, o);
        unsigned long long v1 = shfl_xor_u64(best1, o);
        if (v0 > best0) best0 = v0;
        if (v1 > best1) best1 = v1;
    }
    if (tm == 0) {
        atomicMax(&amax[step * 32 + b0],     best0);
        atomicMax(&amax[step * 32 + b0 + 1], best1);
    }
}

__global__ __launch_bounds__(256)
void logits_fin(const float* part, const void* bout, void* dout,
                unsigned long long* amax, int step, const int* __restrict__ dtf)
{
    int f = *dtf;
    if (f) logfin_body<unsigned short>(part, (const unsigned short*)bout, dout, amax, step, f);
    else   logfin_body<float>(part, (const float*)bout, dout, amax, step, f);
}

template<typename T>
static __device__ __forceinline__
void mean_body(const T* __restrict__ feat, float* __restrict__ meanT)
{
    int e = blockIdx.x * 256 + threadIdx.x;
    int f = e % 1280, b = e / 1280;
    const T* p = feat + (size_t)b * 64 * 1280 + f;
    float s = 0.f;
    for (int nn = 0; nn < 64; ++nn) s += toF(p[(size_t)nn * 1280]);
    meanT[f * 32 + b] = s * (1.f / 64.f);
}
__global__ __launch_bounds__(256)
void init_mean(const void* feat, float* meanT, const int* __restrict__ dtf)
{
    if (*dtf) mean_body<unsigned short>((const unsigned short*)feat, meanT);
    else      mean_body<float>((const float*)feat, meanT);
}

template<typename T>
static __device__ __forceinline__
void inithc_body(const float* __restrict__ meanT, const T* __restrict__ Wh,
                 const T* __restrict__ bh, const T* __restrict__ Wc,
                 const T* __restrict__ bc, float* __restrict__ actT_h, float* __restrict__ cT)
{
    int mb = blockIdx.x >> 2, bq = blockIdx.x & 3;
    int tid = threadIdx.x, tm = tid & 31;
    int m0 = mb * 128 + tm * 4;
    int b = bq * 8 + (tid >> 5);
    bool isH = (m0 < 512);
    const T* W = isH ? Wh : Wc;
    int mw = isH ? m0 : (m0 - 512);
    float a0=0.f,a1=0.f,a2=0.f,a3=0.f;
    const float* ap = meanT + b;
    const T* wp = W + mw;
    #pragma unroll 8
    for (int k = 0; k < 1280; ++k) {
        float av = *ap;
        F4v w = ld4(wp);
        a0 += w.x * av; a1 += w.y * av; a2 += w.z * av; a3 += w.w * av;
        ap += 32; wp += 512;
    }
    const T* bias = isH ? bh : bc;
    float* dst = isH ? actT_h : cT;
    dst[(mw + 0) * 32 + b] = a0 + toF(bias[mw + 0]);
    dst[(mw + 1) * 32 + b] = a1 + toF(bias[mw + 1]);
    dst[(mw + 2) * 32 + b] = a2 + toF(bias[mw + 2]);
    dst[(mw + 3) * 32 + b] = a3 + toF(bias[mw + 3]);
}
__global__ __launch_bounds__(256)
void init_hc(const float* meanT, const void* Wh, const void* bh, const void* Wc,
             const void* bc, float* actT_h, float* cT, const int* __restrict__ dtf)
{
    if (*dtf) inithc_body<unsigned short>(meanT, (const unsigned short*)Wh,
                  (const unsigned short*)bh, (const unsigned short*)Wc,
                  (const unsigned short*)bc, actT_h, cT);
    else      inithc_body<float>(meanT, (const float*)Wh, (const float*)bh,
                  (const float*)Wc, (const float*)bc, actT_h, cT);
}

template<typename T>
static __device__ __forceinline__
void encproj_body(const T* __restrict__ feat, const T* __restrict__ W2,
                  const T* __restrict__ b2, float* __restrict__ encT)
{
    int jb = blockIdx.x & 3, rowb = blockIdx.x >> 2;
    int tid = threadIdx.x, tm = tid & 31, bg = tid >> 5;
    int j0 = jb * 128 + tm * 4;
    int r0 = rowb * 16 + bg * 2;
    float a00=0.f,a01=0.f,a10=0.f,a11=0.f,a20=0.f,a21=0.f,a30=0.f,a31=0.f;
    const T* f0 = feat + (size_t)r0 * 1280;
    const T* f1 = f0 + 1280;
    const T* wp = W2 + j0;
    #pragma unroll 8
    for (int k = 0; k < 1280; ++k) {
        float ax = toF(f0[k]), ay = toF(f1[k]);
        F4v w = ld4(wp);
        a00 += w.x * ax; a01 += w.x * ay;
        a10 += w.y * ax; a11 += w.y * ay;
        a20 += w.z * ax; a21 += w.z * ay;
        a30 += w.w * ax; a31 += w.w * ay;
        wp += 512;
    }
    int b = r0 >> 6, n = r0 & 63;
    float* base = encT + (size_t)b * 32768 + n;
    float bb;
    bb = toF(b2[j0 + 0]); *(float2*)(base + (size_t)(j0 + 0) * 64) = make_float2(a00 + bb, a01 + bb);
    bb = toF(b2[j0 + 1]); *(float2*)(base + (size_t)(j0 + 1) * 64) = make_float2(a10 + bb, a11 + bb);
    bb = toF(b2[j0 + 2]); *(float2*)(base + (size_t)(j0 + 2) * 64) = make_float2(a20 + bb, a21 + bb);
    bb = toF(b2[j0 + 3]); *(float2*)(base + (size_t)(j0 + 3) * 64) = make_float2(a30 + bb, a31 + bb);
}
__global__ __launch_bounds__(256)
void encproj(const void* feat, const void* W2, const void* b2, float* encT,
             const int* __restrict__ dtf)
{
    if (*dtf) encproj_body<unsigned short>((const unsigned short*)feat,
                  (const unsigned short*)W2, (const unsigned short*)b2, encT);
    else      encproj_body<float>((const float*)feat, (const float*)W2,
                  (const float*)b2, encT);
}

static void launch_legacy(void* const* d_in, void* d_out, void* d_ws, hipStream_t stream)
{
    const void* feat  = d_in[0];
    const void* emb   = d_in[3];
    const void* W1    = d_in[4];
    const void* b1    = d_in[5];
    const void* W2    = d_in[6];
    const void* b2    = d_in[7];
    const void* Va    = d_in[8];
    const void* bVa   = d_in[9];
    const void* Wh    = d_in[10];
    const void* bh    = d_in[11];
    const void* Wc    = d_in[12];
    const void* bc    = d_in[13];
    const void* Wg    = d_in[14];
    const void* bg    = d_in[15];
    const void* Wx    = d_in[16];
    const void* Whh   = d_in[17];
    const void* blstm = d_in[18];
    const void* Wout  = d_in[19];
    const void* bout  = d_in[20];

    float* ws         = (float*)d_ws;
    float* encT       = ws;
    float* meanT      = encT + 1048576;
    float* actT_h     = meanT + 40960;
    float* cT         = actT_h + 16384;
    float* hq_part    = cT + 16384;
    float* gate_part  = hq_part + 65536;
    float* gates_part = gate_part + 163840;
    float* ctxgT      = gates_part + 1179648;
    unsigned long long* amax = (unsigned long long*)(ctxgT + 40960);
    int* dtf          = (int*)(amax + 2560);
    float* k4part     = hq_part;

    detect_init<<<1, 256, 0, stream>>>((const unsigned short*)feat, dtf, amax);
    init_mean<<<160, 256, 0, stream>>>(feat, meanT, dtf);
    init_hc  <<<32, 256, 0, stream>>>(meanT, Wh, bh, Wc, bc, actT_h, cT, dtf);
    encproj  <<<512, 256, 0, stream>>>(feat, W2, b2, encT, dtf);

    SkArgs k1{};
    k1.r[0] = { W1,  nullptr, actT_h, hq_part,    512, 4, 128,  512, 0,  32 };
    k1.r[1] = { Wg,  nullptr, actT_h, gate_part, 1280, 4, 128, 1280, 0,  80 };
    k1.r[2] = { Whh, Wx,      actT_h, gates_part,2048, 8, 128, 2048, 1, 256 };
    k1.nReg = 3;
    SkArgs k3{};
    k3.r[0] = { Wx, nullptr, ctxgT,
                gates_part + (size_t)8 * 2048 * 32, 2048, 10, 128, 2048, 3, 320 };
    k3.nReg = 1;
    SkArgs k4{};
    k4.r[0] = { Wout, nullptr, actT_h, k4part, 10000, 4, 128, 10000, 0, 632 };
    k4.nReg = 1;

    for (int t = 0; t < 80; ++t) {
        skgemm     <<<368, 256,  0, stream>>>(k1, t, amax, emb, dtf);
        attn_kernel<<<32,  1024, 0, stream>>>(hq_part, gate_part, encT, feat,
                                              b1, Va, bVa, bg, ctxgT, d_out, t, dtf);
        skgemm     <<<320, 256,  0, stream>>>(k3, t, amax, emb, dtf);
        lstm_pw    <<<64,  256,  0, stream>>>(gates_part, blstm, cT, actT_h, d_out, t, dtf);
        skgemm     <<<632, 256,  0, stream>>>(k4, t, amax, emb, dtf);
        logits_fin <<<158, 256,  0, stream>>>(k4part, bout, d_out, amax, t, dtf);
    }
}

// ---------------------------------------------------------------------------
extern "C" void kernel_launch(void* const* d_in, const int* in_sizes, int n_in,
                              void* d_out, int out_size, void* d_ws, size_t ws_size,
                              hipStream_t stream)
{
    (void)in_sizes; (void)n_in; (void)out_size; (void)ws_size;

    PArgs A;
    A.feat = d_in[0];  A.emb  = d_in[3];
    A.W1   = d_in[4];  A.b1   = d_in[5];
    A.W2   = d_in[6];  A.b2   = d_in[7];
    A.Va   = d_in[8];  A.bVa  = d_in[9];
    A.Wh   = d_in[10]; A.bh   = d_in[11];
    A.Wc   = d_in[12]; A.bc   = d_in[13];
    A.Wg   = d_in[14]; A.bg   = d_in[15];
    A.Wx   = d_in[16]; A.Whh  = d_in[17];
    A.blstm = d_in[18];
    A.Wout = d_in[19]; A.bout = d_in[20];
    A.dout = d_out;
    A.ws   = (float*)d_ws;

    void* kargs[1] = { (void*)&A };
    hipError_t err = hipLaunchCooperativeKernel(
        (const void*)decoder_persistent, dim3(256), dim3(1024), kargs, 0, stream);
    if (err != hipSuccess) {
        (void)hipGetLastError();   // clear error state, fall back to legacy path
        launch_legacy(d_in, d_out, d_ws, stream);
    }
}

// Round 3
// 12933.104 us; speedup vs baseline: 2.4074x; 1.8060x over previous
//
#include <hip/hip_runtime.h>
#include <hip/hip_cooperative_groups.h>

namespace cg = cooperative_groups;

// ---------------------------------------------------------------------------
// DecoderLSTM: B=32, N=64, F=1280, H=512, E=512, V=10000, T=80, SOS=1
// R7: persistent kernel, DENSE handoff. R6 failed on access-pattern
// amplification: 8B/lane stride-128B agent loads used 1/8 of each line ->
// 10.5 GB FETCH at 515 GB/s. Fix: all cross-phase arrays are b-major
// ([kc][b][m], actT_h[b][j], ctxg[b][f]) so every agent access is a dense
// full-line row; act is staged once per BLOCK into LDS (64 KB linear copy,
// broadcast ds_read in the MAC loop); logits re-k-split for load balance
// (<=1 chunk/wave in phase A), finalized in phase B; emb-gather in phase C.
// Barrier: 8 line-separated monotonic counters (32 adds each) + spin.
//   out layout (elements): logits[0,25.6M) h[+16384] c[+16384] attn[+163840]
// ---------------------------------------------------------------------------

#define OFF_H    25600000ull
#define OFF_C    25616384ull
#define OFF_ATTN 25632768ull

// workspace float offsets (no aliasing)
#define WS_ENCT   0ull
#define WS_MEANT  1048576ull
#define WS_ACT    1089536ull     // [32][512]
#define WS_CT     1105920ull     // [32][512]
#define WS_HQ     1122304ull     // [4][32][512]
#define WS_GATE   1187840ull     // [4][32][1280]
#define WS_GATES  1351680ull     // [18][32][2048]
#define WS_CTXG   2531328ull     // [32][1280]
#define WS_K4     2572288ull     // [4][32][10000]
#define WS_AMAX   3852288ull     // u64[2560]
#define WS_BAR    3857408ull     // u64[64] (8 counters, 64B apart)
#define WS_TOTAL_BYTES (3857536ull * 4ull)

struct __align__(8) U16x4 { unsigned short x, y, z, w; };
struct F4v { float x, y, z, w; };

static __device__ __forceinline__ float bf2f(unsigned short u) {
    return __uint_as_float(((unsigned)u) << 16);
}
static __device__ __forceinline__ unsigned short f2bf(float f) {
    unsigned u = __float_as_uint(f);
    u = (u + 0x7FFFu + ((u >> 16) & 1u)) >> 16;
    return (unsigned short)u;
}
static __device__ __forceinline__ float sigf(float x) { return 1.f / (1.f + expf(-x)); }

static __device__ __forceinline__ float toF(unsigned short u) { return bf2f(u); }
static __device__ __forceinline__ float toF(float f) { return f; }
static __device__ __forceinline__ F4v ld4(const unsigned short* p) {
    U16x4 v = *(const U16x4*)p;
    return { bf2f(v.x), bf2f(v.y), bf2f(v.z), bf2f(v.w) };
}
static __device__ __forceinline__ F4v ld4(const float* p) {
    float4 v = *(const float4*)p;
    return { v.x, v.y, v.z, v.w };
}

static __device__ __forceinline__ void stw(void* o, size_t i, float v, int obf) {
    if (obf) ((unsigned short*)o)[i] = f2bf(v);
    else     ((float*)o)[i] = v;
}

static __device__ __forceinline__ unsigned long long packv(float v, int m) {
    unsigned u = __float_as_uint(v);
    u = (u & 0x80000000u) ? ~u : (u | 0x80000000u);
    return ((unsigned long long)u << 32) | (unsigned long long)(0xFFFFFFFFu - (unsigned)m);
}
static __device__ __forceinline__ unsigned long long shfl_xor_u64(unsigned long long v, int o) {
    unsigned hi = (unsigned)(v >> 32), lo = (unsigned)v;
    hi = __shfl_xor(hi, o); lo = __shfl_xor(lo, o);
    return ((unsigned long long)hi << 32) | lo;
}

// ---- agent-scope coherent access (cross-XCD visible, no cache inv) ---------
static __device__ __forceinline__ float aldf(const float* p) {
    return __hip_atomic_load(p, __ATOMIC_RELAXED, __HIP_MEMORY_SCOPE_AGENT);
}
static __device__ __forceinline__ void astf(float* p, float v) {
    __hip_atomic_store(p, v, __ATOMIC_RELAXED, __HIP_MEMORY_SCOPE_AGENT);
}
static __device__ __forceinline__ unsigned long long aldu64(const unsigned long long* p) {
    return __hip_atomic_load(p, __ATOMIC_RELAXED, __HIP_MEMORY_SCOPE_AGENT);
}
static __device__ __forceinline__ void astu64(unsigned long long* p, unsigned long long v) {
    __hip_atomic_store(p, v, __ATOMIC_RELAXED, __HIP_MEMORY_SCOPE_AGENT);
}
static __device__ __forceinline__ void ast2(float* p, float a, float b) {
    union { float f[2]; unsigned long long u; } c; c.f[0] = a; c.f[1] = b;
    astu64((unsigned long long*)p, c.u);
}

// ---- grid barrier: 8 line-separated monotonic counters ---------------------
static __device__ __forceinline__
void gbar(unsigned long long* bar, unsigned long long epoch, int NB)
{
    __syncthreads();
    if (threadIdx.x == 0) {
        __hip_atomic_fetch_add(bar + (blockIdx.x & 7) * 8, 1ull,
                               __ATOMIC_RELAXED, __HIP_MEMORY_SCOPE_AGENT);
        const unsigned long long tgt = epoch * (unsigned long long)NB;
        for (;;) {
            unsigned long long s = 0;
            #pragma unroll
            for (int i = 0; i < 8; ++i) s += aldu64(bar + i * 8);
            if (s >= tgt) break;
            __builtin_amdgcn_s_sleep(2);
        }
    }
    __syncthreads();
}

// ===========================================================================
// Persistent cooperative path
// ===========================================================================

struct PArgs {
    const void* feat; const void* emb;
    const void* W1;  const void* b1;  const void* W2;  const void* b2;
    const void* Va;  const void* bVa; const void* Wh;  const void* bh;
    const void* Wc;  const void* bc;  const void* Wg;  const void* bg;
    const void* Wx;  const void* Whh; const void* blstm;
    const void* Wout; const void* bout;
    void* dout; float* ws;
};

// GEMM over one 128-k chunk from block LDS act. pA/pB: act rows for b0/b0+1
// (broadcast reads). Writes dense b-major partial rows via agent stores.
template<typename T>
static __device__ __forceinline__
void gemm_unit_lds(const float* __restrict__ pA, const float* __restrict__ pB,
                   const T* __restrict__ wp, int ldw, float* __restrict__ pp, int M)
{
    float a0=0.f,a1=0.f,a2=0.f,a3=0.f,a4=0.f,a5=0.f,a6=0.f,a7=0.f;
    #pragma unroll 8
    for (int r = 0; r < 128; ++r) {
        float ax = pA[r], ay = pB[r];
        F4v w = ld4(wp);
        a0 += w.x * ax; a1 += w.x * ay;
        a2 += w.y * ax; a3 += w.y * ay;
        a4 += w.z * ax; a5 += w.z * ay;
        a6 += w.w * ax; a7 += w.w * ay;
        wp += ldw;
    }
    ast2(pp,         a0, a2); ast2(pp + 2,     a4, a6);
    ast2(pp + M,     a1, a3); ast2(pp + M + 2, a5, a7);
}

// stage actT_h [32][512] f32 -> LDS linear copy (dense agent loads)
static __device__ __forceinline__
void stage_act(float* smem, const float* actT_h, int wvb, int lane)
{
    const unsigned long long* src = (const unsigned long long*)actT_h;
    unsigned long long* dst = (unsigned long long*)smem;
    const int base = wvb * 512 + lane;
    unsigned long long r[8];
    #pragma unroll
    for (int i = 0; i < 8; ++i) r[i] = aldu64(src + base + i * 64);
    #pragma unroll
    for (int i = 0; i < 8; ++i) dst[base + i * 64] = r[i];
}

// stage one ctxg chunk kc ([32][128] slice of [32][1280]) into LDS slot
static __device__ __forceinline__
void stage_ctx(float* dstF, const float* ctxg, int kc, int wvb, int lane)
{
    unsigned long long* dst = (unsigned long long*)dstF;
    #pragma unroll
    for (int it = 0; it < 2; ++it) {
        int n = wvb * 128 + it * 64 + lane;     // 0..2047 u64
        int seg = n >> 6;                        // b
        const unsigned long long* src =
            (const unsigned long long*)(ctxg + (size_t)seg * 1280 + kc * 128);
        dst[n] = aldu64(src + (n & 63));
    }
}

// emb-gather GEMM chunk: x(t) @ Wx[0:512]
template<typename T>
static __device__ __forceinline__
void emb_unit(int e, int tm, int half, const T* __restrict__ Wx,
              const T* __restrict__ emb, const unsigned long long* __restrict__ amax,
              int step, float* __restrict__ gates_part)
{
    const int kc = e & 3, rr = e >> 2;
    const int bq = rr & 7, mb = rr >> 3;
    const int m0 = mb * 128 + tm * 4;
    const int b0 = bq * 4 + half * 2;
    const int k0 = kc * 128;
    int idx0 = 1, idx1 = 1;   // SOS at t=0
    if (step > 0) {
        unsigned long long p0 = aldu64(amax + (step - 1) * 32 + b0);
        unsigned long long p1 = aldu64(amax + (step - 1) * 32 + b0 + 1);
        idx0 = (int)(0xFFFFFFFFu - (unsigned)(p0 & 0xFFFFFFFFull));
        idx1 = (int)(0xFFFFFFFFu - (unsigned)(p1 & 0xFFFFFFFFull));
        idx0 &= 0x3FFF; if (idx0 > 9999) idx0 = 9999;
        idx1 &= 0x3FFF; if (idx1 > 9999) idx1 = 9999;
    }
    const T* e0 = emb + (size_t)idx0 * 512 + k0;
    const T* e1 = emb + (size_t)idx1 * 512 + k0;
    const T* wp = Wx + (size_t)k0 * 2048 + m0;
    float a0=0.f,a1=0.f,a2=0.f,a3=0.f,a4=0.f,a5=0.f,a6=0.f,a7=0.f;
    #pragma unroll 8
    for (int k = 0; k < 128; ++k) {
        float ax = toF(e0[k]), ay = toF(e1[k]);
        F4v w = ld4(wp);
        a0 += w.x * ax; a1 += w.x * ay;
        a2 += w.y * ax; a3 += w.y * ay;
        a4 += w.z * ax; a5 += w.z * ay;
        a6 += w.w * ax; a7 += w.w * ay;
        wp += 2048;
    }
    float* pp = gates_part + ((size_t)((4 + kc) * 32 + b0) * 2048 + m0);
    ast2(pp,          a0, a2); ast2(pp + 2,        a4, a6);
    ast2(pp + 2048,   a1, a3); ast2(pp + 2048 + 2, a5, a7);
}

// logits finalize: sum 4 k-partials + bias, store, argmax
template<typename T>
static __device__ __forceinline__
void logfin_unit(int u, int tm, int half, const float* __restrict__ k4part,
                 const T* __restrict__ bout, void* __restrict__ dout,
                 unsigned long long* __restrict__ amax, int step, int obf)
{
    const int mb = u >> 3, bq = u & 7;
    int m0 = mb * 128 + tm * 4;
    if (m0 > 9996) m0 = 9996;                 // tail dup (benign)
    const int b0 = bq * 4 + half * 2;
    float l0[4], l1[4];
    #pragma unroll
    for (int i = 0; i < 4; ++i) { float bb = toF(bout[m0 + i]); l0[i] = bb; l1[i] = bb; }
    #pragma unroll
    for (int kc = 0; kc < 4; ++kc) {
        const float* p0 = k4part + ((size_t)(kc * 32 + b0) * 10000 + m0);
        const float* p1 = p0 + 10000;
        union { unsigned long long u; float f[2]; } q;
        q.u = aldu64((const unsigned long long*)p0);     l0[0] += q.f[0]; l0[1] += q.f[1];
        q.u = aldu64((const unsigned long long*)p0 + 1); l0[2] += q.f[0]; l0[3] += q.f[1];
        q.u = aldu64((const unsigned long long*)p1);     l1[0] += q.f[0]; l1[1] += q.f[1];
        q.u = aldu64((const unsigned long long*)p1 + 1); l1[2] += q.f[0]; l1[3] += q.f[1];
    }
    size_t o0 = ((size_t)(b0    ) * 80 + step) * 10000 + m0;
    size_t o1 = ((size_t)(b0 + 1) * 80 + step) * 10000 + m0;
    if (obf) {
        U16x4 s0 = { f2bf(l0[0]), f2bf(l0[1]), f2bf(l0[2]), f2bf(l0[3]) };
        U16x4 s1 = { f2bf(l1[0]), f2bf(l1[1]), f2bf(l1[2]), f2bf(l1[3]) };
        *(U16x4*)((unsigned short*)dout + o0) = s0;
        *(U16x4*)((unsigned short*)dout + o1) = s1;
    } else {
        *(float4*)((float*)dout + o0) = make_float4(l0[0], l0[1], l0[2], l0[3]);
        *(float4*)((float*)dout + o1) = make_float4(l1[0], l1[1], l1[2], l1[3]);
    }
    unsigned long long best0 = packv(l0[0], m0), best1 = packv(l1[0], m0), p;
    #pragma unroll
    for (int i = 1; i < 4; ++i) {
        p = packv(l0[i], m0 + i); if (p > best0) best0 = p;
        p = packv(l1[i], m0 + i); if (p > best1) best1 = p;
    }
    #pragma unroll
    for (int o = 16; o; o >>= 1) {
        unsigned long long v0 = shfl_xor_u64(best0, o);
        unsigned long long v1 = shfl_xor_u64(best1, o);
        if (v0 > best0) best0 = v0;
        if (v1 > best1) best1 = v1;
    }
    if (tm == 0) {
        atomicMax(&amax[step * 32 + b0],     best0);
        atomicMax(&amax[step * 32 + b0 + 1], best1);
    }
}

// attention: one 1024-thread block per batch row; scratch carved from smem
template<typename T>
static __device__ __forceinline__
void attn_block(int b, int tid, const float* __restrict__ hq_part,
                const float* __restrict__ gate_part, const float* __restrict__ encT,
                const T* __restrict__ feat, const T* __restrict__ b1v,
                const T* __restrict__ Vav, const T* __restrict__ bVav,
                const T* __restrict__ bgv, float* __restrict__ ctxg,
                void* __restrict__ dout, int step, int obf, float* smem)
{
    float* hqL = smem;              // 512
    float* VaL = smem + 512;        // 512
    float* wL  = smem + 1024;       // 64
    float (*sred)[64] = (float(*)[64])(smem + 1088);  // 16x64
    if (tid < 512) {
        float s = toF(b1v[tid]);
        #pragma unroll
        for (int kp = 0; kp < 4; ++kp) s += aldf(hq_part + (size_t)(kp * 32 + b) * 512 + tid);
        hqL[tid] = s;
        VaL[tid] = toF(Vav[tid]);
    }
    __syncthreads();
    {
        const int n = tid & 63, jq = tid >> 6;
        float s = 0.f;
        const float* ep = encT + (size_t)b * 32768 + n;
        #pragma unroll 8
        for (int jj = 0; jj < 32; ++jj) {
            int j = jq * 32 + jj;
            float v = hqL[j] + ep[(size_t)j * 64];
            s += fmaxf(v, 0.f) * VaL[j];
        }
        sred[jq][n] = s;
    }
    __syncthreads();
    if (tid < 64) {
        float s = toF(bVav[0]);
        #pragma unroll
        for (int q = 0; q < 16; ++q) s += sred[q][tid];
        float mx = s;
        for (int o = 32; o; o >>= 1) mx = fmaxf(mx, __shfl_xor(mx, o));
        float e = expf(s - mx);
        float sum = e;
        for (int o = 32; o; o >>= 1) sum += __shfl_xor(sum, o);
        float w = e / sum;
        wL[tid] = w;
        stw(dout, OFF_ATTN + ((size_t)b * 80 + step) * 64 + tid, w, obf);
    }
    __syncthreads();
    const T* fp = feat + (size_t)b * 64 * 1280;
    {
        float c0 = 0.f;
        #pragma unroll 8
        for (int nn = 0; nn < 64; ++nn) c0 += wL[nn] * toF(fp[nn * 1280 + tid]);
        float g = toF(bgv[tid]);
        #pragma unroll
        for (int kp = 0; kp < 4; ++kp) g += aldf(gate_part + (size_t)(kp * 32 + b) * 1280 + tid);
        g = 1.f / (1.f + expf(-g));
        astf(ctxg + (size_t)b * 1280 + tid, c0 * g);
    }
    if (tid < 256) {
        int f = 1024 + tid;
        float c1 = 0.f;
        #pragma unroll 8
        for (int nn = 0; nn < 64; ++nn) c1 += wL[nn] * toF(fp[nn * 1280 + f]);
        float g = toF(bgv[f]);
        #pragma unroll
        for (int kp = 0; kp < 4; ++kp) g += aldf(gate_part + (size_t)(kp * 32 + b) * 1280 + f);
        g = 1.f / (1.f + expf(-g));
        astf(ctxg + (size_t)b * 1280 + f, c1 * g);
    }
}

// LSTM pointwise: wave unit w covers b = w>>3, j = (w&7)*64 + lane
template<typename T>
static __device__ __forceinline__
void lstm_unit(int w, int lane, const float* __restrict__ gates_part,
               const T* __restrict__ blstmv, float* __restrict__ cT,
               float* __restrict__ actT_h, void* __restrict__ dout,
               int step, int obf)
{
    const int b = w >> 3, j = (w & 7) * 64 + lane;
    float gi = toF(blstmv[j]),        gf = toF(blstmv[j + 512]);
    float gg = toF(blstmv[j + 1024]), go = toF(blstmv[j + 1536]);
    #pragma unroll
    for (int kc = 0; kc < 18; ++kc) {
        const float* p = gates_part + (size_t)(kc * 32 + b) * 2048;
        gi += aldf(p + j);
        gf += aldf(p + 512 + j);
        gg += aldf(p + 1024 + j);
        go += aldf(p + 1536 + j);
    }
    float c  = cT[b * 512 + j];               // block-local across steps
    float c2 = sigf(gf) * c + sigf(gi) * tanhf(gg);
    float h2 = sigf(go) * tanhf(c2);
    cT[b * 512 + j] = c2;
    astf(actT_h + b * 512 + j, h2);
    if (step == 79) {
        stw(dout, OFF_H + (size_t)b * 512 + j, h2, obf);
        stw(dout, OFF_C + (size_t)b * 512 + j, c2, obf);
    }
}

// ---- init units -------------------------------------------------------------
template<typename T>
static __device__ __forceinline__
void mean_unit(int u, int stid, const T* __restrict__ feat, float* __restrict__ meanT)
{
    int e = u * 256 + stid;                   // 40960 = 32*1280
    int f = e % 1280, b = e / 1280;
    const T* p = feat + (size_t)b * 64 * 1280 + f;
    float s = 0.f;
    for (int nn = 0; nn < 64; ++nn) s += toF(p[(size_t)nn * 1280]);
    meanT[f * 32 + b] = s * (1.f / 64.f);
}

template<typename T>
static __device__ __forceinline__
void inithc_unit(int u, int stid, const float* __restrict__ meanT,
                 const T* __restrict__ Whv, const T* __restrict__ bhv,
                 const T* __restrict__ Wcv, const T* __restrict__ bcv,
                 float* __restrict__ actT_h, float* __restrict__ cT)
{
    int mb = u >> 2, bq = u & 3;
    int tm = stid & 31;
    int m0 = mb * 128 + tm * 4;
    int b = bq * 8 + (stid >> 5);
    bool isH = (m0 < 512);
    const T* W = isH ? Whv : Wcv;
    int mw = isH ? m0 : (m0 - 512);
    float a0=0.f,a1=0.f,a2=0.f,a3=0.f;
    const float* ap = meanT + b;
    const T* wp = W + mw;
    #pragma unroll 8
    for (int k = 0; k < 1280; ++k) {
        float av = *ap;
        F4v w = ld4(wp);
        a0 += w.x * av; a1 += w.y * av; a2 += w.z * av; a3 += w.w * av;
        ap += 32; wp += 512;
    }
    const T* bias = isH ? bhv : bcv;
    float* dst = isH ? actT_h : cT;
    dst[b * 512 + mw + 0] = a0 + toF(bias[mw + 0]);
    dst[b * 512 + mw + 1] = a1 + toF(bias[mw + 1]);
    dst[b * 512 + mw + 2] = a2 + toF(bias[mw + 2]);
    dst[b * 512 + mw + 3] = a3 + toF(bias[mw + 3]);
}

template<typename T>
static __device__ __forceinline__
void encproj_unit(int u, int stid, const T* __restrict__ feat,
                  const T* __restrict__ W2v, const T* __restrict__ b2v,
                  float* __restrict__ encT)
{
    int jb = u & 3, rowb = u >> 2;
    int tm = stid & 31, bg = stid >> 5;
    int j0 = jb * 128 + tm * 4;
    int r0 = rowb * 16 + bg * 2;
    float a00=0.f,a01=0.f,a10=0.f,a11=0.f,a20=0.f,a21=0.f,a30=0.f,a31=0.f;
    const T* f0 = feat + (size_t)r0 * 1280;
    const T* f1 = f0 + 1280;
    const T* wp = W2v + j0;
    #pragma unroll 8
    for (int k = 0; k < 1280; ++k) {
        float ax = toF(f0[k]), ay = toF(f1[k]);
        F4v w = ld4(wp);
        a00 += w.x * ax; a01 += w.x * ay;
        a10 += w.y * ax; a11 += w.y * ay;
        a20 += w.z * ax; a21 += w.z * ay;
        a30 += w.w * ax; a31 += w.w * ay;
        wp += 512;
    }
    int b = r0 >> 6, n = r0 & 63;
    float* base = encT + (size_t)b * 32768 + n;
    float bb;
    bb = toF(b2v[j0 + 0]); *(float2*)(base + (size_t)(j0 + 0) * 64) = make_float2(a00 + bb, a01 + bb);
    bb = toF(b2v[j0 + 1]); *(float2*)(base + (size_t)(j0 + 1) * 64) = make_float2(a10 + bb, a11 + bb);
    bb = toF(b2v[j0 + 2]); *(float2*)(base + (size_t)(j0 + 2) * 64) = make_float2(a20 + bb, a21 + bb);
    bb = toF(b2v[j0 + 3]); *(float2*)(base + (size_t)(j0 + 3) * 64) = make_float2(a30 + bb, a31 + bb);
}

// ---- the persistent driver --------------------------------------------------
template<typename T>
static __device__ void run_all(const PArgs A, int obf, cg::grid_group grid, float* smem)
{
    float* ws         = A.ws;
    float* encT       = ws + WS_ENCT;
    float* meanT      = ws + WS_MEANT;
    float* actT_h     = ws + WS_ACT;
    float* cT         = ws + WS_CT;
    float* hq_part    = ws + WS_HQ;
    float* gate_part  = ws + WS_GATE;
    float* gates_part = ws + WS_GATES;
    float* ctxg       = ws + WS_CTXG;
    float* k4part     = ws + WS_K4;
    unsigned long long* amax = (unsigned long long*)(ws + WS_AMAX);
    unsigned long long* bar  = (unsigned long long*)(ws + WS_BAR);

    const T* featp  = (const T*)A.feat;
    const T* embp   = (const T*)A.emb;
    const T* W1p    = (const T*)A.W1;
    const T* b1p    = (const T*)A.b1;
    const T* W2p    = (const T*)A.W2;
    const T* b2p    = (const T*)A.b2;
    const T* Vap    = (const T*)A.Va;
    const T* bVap   = (const T*)A.bVa;
    const T* Whp    = (const T*)A.Wh;
    const T* bhp    = (const T*)A.bh;
    const T* Wcp    = (const T*)A.Wc;
    const T* bcp    = (const T*)A.bc;
    const T* Wgp    = (const T*)A.Wg;
    const T* bgp    = (const T*)A.bg;
    const T* Wxp    = (const T*)A.Wx;
    const T* Whhp   = (const T*)A.Whh;
    const T* blstmp = (const T*)A.blstm;
    const T* Woutp  = (const T*)A.Wout;
    const T* boutp  = (const T*)A.bout;

    const int NB   = gridDim.x;                 // 256
    const int bk   = blockIdx.x;
    const int lane = threadIdx.x & 63;
    const int wvb  = threadIdx.x >> 6;          // 0..15
    const int gw   = wvb * NB + bk;             // 0..4095
    const int tm   = lane & 31;
    const int half = (lane >> 5) & 1;
    const int nss  = NB * 4;
    const int ss   = (threadIdx.x >> 8) * NB + bk;
    const int stid = threadIdx.x & 255;

    // ---- init (real cg syncs: flush dirty L2 so later agent/normal reads see it)
    {
        int gt = bk * 1024 + threadIdx.x;
        if (gt < 2560) astu64(amax + gt, 0ull);
        if (gt >= 2560 && gt < 2624) astu64(bar + (gt - 2560), 0ull);
    }
    for (int u = ss; u < 160; u += nss) mean_unit(u, stid, featp, meanT);
    for (int u = ss; u < 512; u += nss) encproj_unit(u, stid, featp, W2p, b2p, encT);
    grid.sync();
    for (int u = ss; u < 32; u += nss)
        inithc_unit(u, stid, meanT, Whp, bhp, Wcp, bcp, actT_h, cT);
    grid.sync();

    unsigned long long epoch = 0;

    for (int t = 0; t < 80; ++t) {
        // ---- Phase A: stage act; hq(128)+gate(320)+Whh(512)+logits-ksplit(t-1)(2528)
        stage_act(smem, actT_h, wvb, lane);
        __syncthreads();
        {
            const int uMax = (t > 0) ? 3488 : 960;
            const int u = gw;
            if (u < uMax) {
                const T* W; int ldw, M; float* part; int v;
                if (u < 128)      { v = u;       W = W1p;   ldw = 512;   M = 512;   part = hq_part; }
                else if (u < 448) { v = u - 128; W = Wgp;   ldw = 1280;  M = 1280;  part = gate_part; }
                else if (u < 960) { v = u - 448; W = Whhp;  ldw = 2048;  M = 2048;  part = gates_part; }
                else              { v = u - 960; W = Woutp; ldw = 10000; M = 10000; part = k4part; }
                const int kc = v & 3, rr = v >> 2;
                const int bq = rr & 7, mb = rr >> 3;
                int m0 = mb * 128 + tm * 4; if (m0 > M - 4) m0 = M - 4;
                const int b0 = bq * 4 + half * 2;
                const float* pA = smem + b0 * 512 + kc * 128;
                gemm_unit_lds(pA, pA + 512, W + (size_t)(kc * 128) * ldw + m0, ldw,
                              part + ((size_t)(kc * 32 + b0) * M + m0), M);
            }
        }
        gbar(bar, ++epoch, NB);
        // ---- Phase B: attn on blocks 0..31 | logfin(t-1) on blocks >=32
        if (bk < 32) {
            attn_block(bk, (int)threadIdx.x, hq_part, gate_part, encT, featp,
                       b1p, Vap, bVap, bgp, ctxg, A.dout, t, obf, smem);
        } else if (t > 0) {
            int u = wvb * (NB - 32) + (bk - 32);
            if (u < 632)
                logfin_unit(u, tm, half, k4part, boutp, A.dout, amax, t - 1, obf);
        }
        gbar(bar, ++epoch, NB);
        // ---- Phase C: ctxg @ Wx[512:1792] (block-major, <=2 chunks staged) + emb
        {
            const int u0 = 5 * bk;
            const int kcA = u0 >> 7, kcB = (u0 + 4) >> 7;
            stage_ctx(smem, ctxg, kcA, wvb, lane);
            if (kcB != kcA) stage_ctx(smem + 4096, ctxg, kcB, wvb, lane);
            __syncthreads();
            if (wvb < 5) {
                const int u = u0 + wvb;
                const int kc = u >> 7, rr = u & 127;
                const int bq = rr & 7, mb = rr >> 3;
                const int m0 = mb * 128 + tm * 4;
                const int b0 = bq * 4 + half * 2;
                const float* pA = smem + (kc == kcA ? 0 : 4096) + b0 * 128;
                gemm_unit_lds(pA, pA + 128,
                              Wxp + (size_t)(512 + kc * 128) * 2048 + m0, 2048,
                              gates_part + ((size_t)((8 + kc) * 32 + b0) * 2048 + m0), 2048);
            } else if (wvb < 7) {
                const int e = bk * 2 + (wvb - 5);
                emb_unit(e, tm, half, Wxp, embp, amax, t, gates_part);
            }
        }
        gbar(bar, ++epoch, NB);
        // ---- Phase D: LSTM pointwise (unit bk on wave 0; cT block-local)
        if (wvb == 0) lstm_unit(bk, lane, gates_part, blstmp, cT, actT_h, A.dout, t, obf);
        gbar(bar, ++epoch, NB);
    }
    // ---- final logits for t=79 ----
    stage_act(smem, actT_h, wvb, lane);
    __syncthreads();
    if (gw < 2528) {
        const int v = gw;
        const int kc = v & 3, rr = v >> 2;
        const int bq = rr & 7, mb = rr >> 3;
        int m0 = mb * 128 + tm * 4; if (m0 > 9996) m0 = 9996;
        const int b0 = bq * 4 + half * 2;
        const float* pA = smem + b0 * 512 + kc * 128;
        gemm_unit_lds(pA, pA + 512, Woutp + (size_t)(kc * 128) * 10000 + m0, 10000,
                      k4part + ((size_t)(kc * 32 + b0) * 10000 + m0), 10000);
    }
    gbar(bar, ++epoch, NB);
    if (gw < 632)
        logfin_unit(gw, tm, half, k4part, boutp, A.dout, amax, 79, obf);
}

__global__ __launch_bounds__(1024, 4)
void decoder_persistent(PArgs A)
{
    __shared__ float smem[16384];   // 64 KB: act stage / ctx chunks / attn scratch
    // dtype detect — uniform result in every thread (cheap, once)
    const unsigned short* fU = (const unsigned short*)A.feat;
    int hits = 0;
    for (int i = 0; i < 128; ++i) {
        unsigned e = (fU[2 * i] >> 7) & 0xFF;
        if (e >= 0x70 && e <= 0x8E) ++hits;
    }
    const int dtf = (hits >= 64) ? 1 : 0;       // 1 = bf16, 0 = f32
    cg::grid_group grid = cg::this_grid();
    if (dtf) run_all<unsigned short>(A, 1, grid, smem);
    else     run_all<float>(A, 0, grid, smem);
}

// ===========================================================================
// Legacy multi-kernel fallback (R4 kernel set, verbatim) — used only if the
// cooperative launch is rejected or the workspace is too small.
// ===========================================================================

struct Region {
    const void* W;
    const void* W2;
    const float* actT;
    float* part;
    int M, KS, Kc, ldw, mode, nBlocks;
};
struct SkArgs { Region r[3]; int nReg; };

__global__ __launch_bounds__(256)
void detect_init(const unsigned short* __restrict__ featU, int* __restrict__ dtf,
                 unsigned long long* __restrict__ amax)
{
    if (threadIdx.x == 0) {
        int hits = 0;
        for (int i = 0; i < 128; ++i) {
            unsigned e = (featU[2 * i] >> 7) & 0xFF;
            if (e >= 0x70 && e <= 0x8E) ++hits;
        }
        *dtf = (hits >= 64) ? 1 : 0;
    }
    for (int i = threadIdx.x; i < 2560; i += 256) amax[i] = 0ull;
}

template<typename T>
static __device__ __forceinline__
void skgemm_body(const SkArgs& a, int step, const unsigned long long* __restrict__ amax,
                 const T* __restrict__ emb)
{
    int local = blockIdx.x;
    Region R = a.r[0];
    if (a.nReg > 1 && local >= R.nBlocks) {
        local -= R.nBlocks; R = a.r[1];
        if (a.nReg > 2 && local >= R.nBlocks) { local -= R.nBlocks; R = a.r[2]; }
    }
    const int kc    = local % R.KS;
    const int rr    = local / R.KS;
    const int bHalf = rr & 1;
    const int mb    = rr >> 1;
    const int tid = threadIdx.x;
    const int tm = tid & 31, bg = tid >> 5;
    int m0 = mb * 128 + tm * 4;
    if (m0 > R.M - 4) m0 = R.M - 4;
    const int b0 = bHalf * 16 + bg * 2;
    const int k0 = kc * R.Kc;
    const int rowOff = (R.mode == 3) ? 512 : 0;

    float a00=0.f,a01=0.f,a10=0.f,a11=0.f,a20=0.f,a21=0.f,a30=0.f,a31=0.f;

    const bool gather = (R.mode == 1) && (k0 >= 512);
    const T* wp = (gather ? ((const T*)R.W2 + (size_t)(k0 - 512) * R.ldw)
                          : ((const T*)R.W  + (size_t)(k0 + rowOff) * R.ldw)) + m0;
    if (!gather) {
        const float* ap = R.actT + (size_t)k0 * 32 + b0;
        #pragma unroll 8
        for (int k = 0; k < R.Kc; ++k) {
            float2 av = *(const float2*)ap;
            F4v w = ld4(wp);
            a00 += w.x * av.x; a01 += w.x * av.y;
            a10 += w.y * av.x; a11 += w.y * av.y;
            a20 += w.z * av.x; a21 += w.z * av.y;
            a30 += w.w * av.x; a31 += w.w * av.y;
            ap += 32; wp += R.ldw;
        }
    } else {
        int idx0 = 1, idx1 = 1;
        if (step > 0) {
            unsigned long long p0 = amax[(step - 1) * 32 + b0];
            unsigned long long p1 = amax[(step - 1) * 32 + b0 + 1];
            idx0 = (int)(0xFFFFFFFFu - (unsigned)(p0 & 0xFFFFFFFFull));
            idx1 = (int)(0xFFFFFFFFu - (unsigned)(p1 & 0xFFFFFFFFull));
            idx0 &= 0x3FFF; if (idx0 > 9999) idx0 = 9999;
            idx1 &= 0x3FFF; if (idx1 > 9999) idx1 = 9999;
        }
        const T* e0 = emb + (size_t)idx0 * 512 + (k0 - 512);
        const T* e1 = emb + (size_t)idx1 * 512 + (k0 - 512);
        #pragma unroll 8
        for (int k = 0; k < R.Kc; ++k) {
            float ax = toF(e0[k]), ay = toF(e1[k]);
            F4v w = ld4(wp);
            a00 += w.x * ax; a01 += w.x * ay;
            a10 += w.y * ax; a11 += w.y * ay;
            a20 += w.z * ax; a21 += w.z * ay;
            a30 += w.w * ax; a31 += w.w * ay;
            wp += R.ldw;
        }
    }
    float* pp = R.part + ((size_t)kc * R.M + m0) * 32 + b0;
    *(float2*)(pp)      = make_float2(a00, a01);
    *(float2*)(pp + 32) = make_float2(a10, a11);
    *(float2*)(pp + 64) = make_float2(a20, a21);
    *(float2*)(pp + 96) = make_float2(a30, a31);
}

__global__ __launch_bounds__(256)
void skgemm(SkArgs a, int step, const unsigned long long* __restrict__ amax,
            const void* __restrict__ emb, const int* __restrict__ dtf)
{
    if (*dtf) skgemm_body<unsigned short>(a, step, amax, (const unsigned short*)emb);
    else      skgemm_body<float>(a, step, amax, (const float*)emb);
}

template<typename T>
static __device__ __forceinline__
void attn_body(const float* __restrict__ hq_part, const float* __restrict__ gate_part,
               const float* __restrict__ encT, const T* __restrict__ feat,
               const T* __restrict__ b1, const T* __restrict__ Va,
               const T* __restrict__ bVa, const T* __restrict__ bg_,
               float* __restrict__ ctxgT, void* __restrict__ dout, int step, int obf)
{
    __shared__ float hqL[512], VaL[512], wL[64], sred[16][64];
    const int b = blockIdx.x, tid = threadIdx.x;
    if (tid < 512) {
        float s = toF(b1[tid]);
        #pragma unroll
        for (int kp = 0; kp < 4; ++kp) s += hq_part[kp * 16384 + tid * 32 + b];
        hqL[tid] = s;
        VaL[tid] = toF(Va[tid]);
    }
    __syncthreads();
    {
        const int n = tid & 63, jq = tid >> 6;
        float s = 0.f;
        const float* ep = encT + (size_t)b * 32768 + n;
        #pragma unroll 8
        for (int jj = 0; jj < 32; ++jj) {
            int j = jq * 32 + jj;
            float v = hqL[j] + ep[(size_t)j * 64];
            s += fmaxf(v, 0.f) * VaL[j];
        }
        sred[jq][n] = s;
    }
    __syncthreads();
    if (tid < 64) {
        float s = toF(bVa[0]);
        #pragma unroll
        for (int q = 0; q < 16; ++q) s += sred[q][tid];
        float mx = s;
        for (int o = 32; o; o >>= 1) mx = fmaxf(mx, __shfl_xor(mx, o));
        float e = expf(s - mx);
        float sum = e;
        for (int o = 32; o; o >>= 1) sum += __shfl_xor(sum, o);
        float w = e / sum;
        wL[tid] = w;
        stw(dout, OFF_ATTN + ((size_t)b * 80 + step) * 64 + tid, w, obf);
    }
    __syncthreads();
    const T* fp = feat + (size_t)b * 64 * 1280;
    {
        float c0 = 0.f;
        #pragma unroll 8
        for (int nn = 0; nn < 64; ++nn) c0 += wL[nn] * toF(fp[nn * 1280 + tid]);
        float g = toF(bg_[tid]);
        #pragma unroll
        for (int kp = 0; kp < 4; ++kp) g += gate_part[kp * 40960 + tid * 32 + b];
        g = 1.f / (1.f + expf(-g));
        ctxgT[tid * 32 + b] = c0 * g;
    }
    if (tid < 256) {
        int f = 1024 + tid;
        float c1 = 0.f;
        #pragma unroll 8
        for (int nn = 0; nn < 64; ++nn) c1 += wL[nn] * toF(fp[nn * 1280 + f]);
        float g = toF(bg_[f]);
        #pragma unroll
        for (int kp = 0; kp < 4; ++kp) g += gate_part[kp * 40960 + f * 32 + b];
        g = 1.f / (1.f + expf(-g));
        ctxgT[f * 32 + b] = c1 * g;
    }
}

__global__ __launch_bounds__(1024)
void attn_kernel(const float* hq_part, const float* gate_part, const float* encT,
                 const void* feat, const void* b1, const void* Va, const void* bVa,
                 const void* bg_, float* ctxgT, void* dout, int step,
                 const int* __restrict__ dtf)
{
    int f = *dtf;
    if (f) attn_body<unsigned short>(hq_part, gate_part, encT,
               (const unsigned short*)feat, (const unsigned short*)b1,
               (const unsigned short*)Va, (const unsigned short*)bVa,
               (const unsigned short*)bg_, ctxgT, dout, step, f);
    else   attn_body<float>(hq_part, gate_part, encT,
               (const float*)feat, (const float*)b1, (const float*)Va,
               (const float*)bVa, (const float*)bg_, ctxgT, dout, step, f);
}

template<typename T>
static __device__ __forceinline__
void lstm_body(const float* __restrict__ gates_part, const T* __restrict__ blstm,
               float* __restrict__ cT, float* __restrict__ actT_h,
               void* __restrict__ dout, int step, int obf)
{
    int g = blockIdx.x * 256 + threadIdx.x;
    int b = g & 31, j = g >> 5;
    float gi = toF(blstm[j]),        gf = toF(blstm[j + 512]);
    float gg = toF(blstm[j + 1024]), go = toF(blstm[j + 1536]);
    #pragma unroll
    for (int kc = 0; kc < 18; ++kc) {
        const float* p = gates_part + (size_t)kc * 2048 * 32;
        gi += p[(j       ) * 32 + b];
        gf += p[(j +  512) * 32 + b];
        gg += p[(j + 1024) * 32 + b];
        go += p[(j + 1536) * 32 + b];
    }
    float c  = cT[j * 32 + b];
    float c2 = sigf(gf) * c + sigf(gi) * tanhf(gg);
    float h2 = sigf(go) * tanhf(c2);
    cT[j * 32 + b] = c2;
    actT_h[j * 32 + b] = h2;
    if (step == 79) {
        stw(dout, OFF_H + (size_t)b * 512 + j, h2, obf);
        stw(dout, OFF_C + (size_t)b * 512 + j, c2, obf);
    }
}

__global__ __launch_bounds__(256)
void lstm_pw(const float* gates_part, const void* blstm, float* cT, float* actT_h,
             void* dout, int step, const int* __restrict__ dtf)
{
    int f = *dtf;
    if (f) lstm_body<unsigned short>(gates_part, (const unsigned short*)blstm,
                                     cT, actT_h, dout, step, f);
    else   lstm_body<float>(gates_part, (const float*)blstm, cT, actT_h, dout, step, f);
}

template<typename T>
static __device__ __forceinline__
void logfin_body(const float* __restrict__ part, const T* __restrict__ bout,
                 void* __restrict__ dout, unsigned long long* __restrict__ amax,
                 int step, int obf)
{
    const int mb = blockIdx.x >> 1, bHalf = blockIdx.x & 1;
    const int tid = threadIdx.x, tm = tid & 31, bg = tid >> 5;
    int m0 = mb * 128 + tm * 4;
    if (m0 > 9996) m0 = 9996;
    const int b0 = bHalf * 16 + bg * 2;

    float l0[4], l1[4];
    #pragma unroll
    for (int i = 0; i < 4; ++i) { float bb = toF(bout[m0 + i]); l0[i] = bb; l1[i] = bb; }
    #pragma unroll
    for (int kc = 0; kc < 4; ++kc) {
        const float* p = part + ((size_t)kc * 10000 + m0) * 32 + b0;
        #pragma unroll
        for (int i = 0; i < 4; ++i) { l0[i] += p[i * 32]; l1[i] += p[i * 32 + 1]; }
    }
    size_t o0 = ((size_t)(b0    ) * 80 + step) * 10000 + m0;
    size_t o1 = ((size_t)(b0 + 1) * 80 + step) * 10000 + m0;
    if (obf) {
        U16x4 s0 = { f2bf(l0[0]), f2bf(l0[1]), f2bf(l0[2]), f2bf(l0[3]) };
        U16x4 s1 = { f2bf(l1[0]), f2bf(l1[1]), f2bf(l1[2]), f2bf(l1[3]) };
        *(U16x4*)((unsigned short*)dout + o0) = s0;
        *(U16x4*)((unsigned short*)dout + o1) = s1;
    } else {
        *(float4*)((float*)dout + o0) = make_float4(l0[0], l0[1], l0[2], l0[3]);
        *(float4*)((float*)dout + o1) = make_float4(l1[0], l1[1], l1[2], l1[3]);
    }
    unsigned long long best0 = packv(l0[0], m0), best1 = packv(l1[0], m0), p;
    #pragma unroll
    for (int i = 1; i < 4; ++i) {
        p = packv(l0[i], m0 + i); if (p > best0) best0 = p;
        p = packv(l1[i], m0 + i); if (p > best1) best1 = p;
    }
    #pragma unroll
    for (int o = 16; o; o >>= 1) {
        unsigned long long v0 = shfl_xor_u64(best0, o);
        unsigned long long v1 = shfl_xor_u64(best1, o);
        if (v0 > best0) best0 = v0;
        if (v1 > best1) best1 = v1;
    }
    if (tm == 0) {
        atomicMax(&amax[step * 32 + b0],     best0);
        atomicMax(&amax[step * 32 + b0 + 1], best1);
    }
}

__global__ __launch_bounds__(256)
void logits_fin(const float* part, const void* bout, void* dout,
                unsigned long long* amax, int step, const int* __restrict__ dtf)
{
    int f = *dtf;
    if (f) logfin_body<unsigned short>(part, (const unsigned short*)bout, dout, amax, step, f);
    else   logfin_body<float>(part, (const float*)bout, dout, amax, step, f);
}

template<typename T>
static __device__ __forceinline__
void mean_body(const T* __restrict__ feat, float* __restrict__ meanT)
{
    int e = blockIdx.x * 256 + threadIdx.x;
    int f = e % 1280, b = e / 1280;
    const T* p = feat + (size_t)b * 64 * 1280 + f;
    float s = 0.f;
    for (int nn = 0; nn < 64; ++nn) s += toF(p[(size_t)nn * 1280]);
    meanT[f * 32 + b] = s * (1.f / 64.f);
}
__global__ __launch_bounds__(256)
void init_mean(const void* feat, float* meanT, const int* __restrict__ dtf)
{
    if (*dtf) mean_body<unsigned short>((const unsigned short*)feat, meanT);
    else      mean_body<float>((const float*)feat, meanT);
}

template<typename T>
static __device__ __forceinline__
void inithc_body(const float* __restrict__ meanT, const T* __restrict__ Wh,
                 const T* __restrict__ bh, const T* __restrict__ Wc,
                 const T* __restrict__ bc, float* __restrict__ actT_h, float* __restrict__ cT)
{
    int mb = blockIdx.x >> 2, bq = blockIdx.x & 3;
    int tid = threadIdx.x, tm = tid & 31;
    int m0 = mb * 128 + tm * 4;
    int b = bq * 8 + (tid >> 5);
    bool isH = (m0 < 512);
    const T* W = isH ? Wh : Wc;
    int mw = isH ? m0 : (m0 - 512);
    float a0=0.f,a1=0.f,a2=0.f,a3=0.f;
    const float* ap = meanT + b;
    const T* wp = W + mw;
    #pragma unroll 8
    for (int k = 0; k < 1280; ++k) {
        float av = *ap;
        F4v w = ld4(wp);
        a0 += w.x * av; a1 += w.y * av; a2 += w.z * av; a3 += w.w * av;
        ap += 32; wp += 512;
    }
    const T* bias = isH ? bh : bc;
    float* dst = isH ? actT_h : cT;
    dst[(mw + 0) * 32 + b] = a0 + toF(bias[mw + 0]);
    dst[(mw + 1) * 32 + b] = a1 + toF(bias[mw + 1]);
    dst[(mw + 2) * 32 + b] = a2 + toF(bias[mw + 2]);
    dst[(mw + 3) * 32 + b] = a3 + toF(bias[mw + 3]);
}
__global__ __launch_bounds__(256)
void init_hc(const float* meanT, const void* Wh, const void* bh, const void* Wc,
             const void* bc, float* actT_h, float* cT, const int* __restrict__ dtf)
{
    if (*dtf) inithc_body<unsigned short>(meanT, (const unsigned short*)Wh,
                  (const unsigned short*)bh, (const unsigned short*)Wc,
                  (const unsigned short*)bc, actT_h, cT);
    else      inithc_body<float>(meanT, (const float*)Wh, (const float*)bh,
                  (const float*)Wc, (const float*)bc, actT_h, cT);
}

template<typename T>
static __device__ __forceinline__
void encproj_body(const T* __restrict__ feat, const T* __restrict__ W2,
                  const T* __restrict__ b2, float* __restrict__ encT)
{
    int jb = blockIdx.x & 3, rowb = blockIdx.x >> 2;
    int tid = threadIdx.x, tm = tid & 31, bg = tid >> 5;
    int j0 = jb * 128 + tm * 4;
    int r0 = rowb * 16 + bg * 2;
    float a00=0.f,a01=0.f,a10=0.f,a11=0.f,a20=0.f,a21=0.f,a30=0.f,a31=0.f;
    const T* f0 = feat + (size_t)r0 * 1280;
    const T* f1 = f0 + 1280;
    const T* wp = W2 + j0;
    #pragma unroll 8
    for (int k = 0; k < 1280; ++k) {
        float ax = toF(f0[k]), ay = toF(f1[k]);
        F4v w = ld4(wp);
        a00 += w.x * ax; a01 += w.x * ay;
        a10 += w.y * ax; a11 += w.y * ay;
        a20 += w.z * ax; a21 += w.z * ay;
        a30 += w.w * ax; a31 += w.w * ay;
        wp += 512;
    }
    int b = r0 >> 6, n = r0 & 63;
    float* base = encT + (size_t)b * 32768 + n;
    float bb;
    bb = toF(b2[j0 + 0]); *(float2*)(base + (size_t)(j0 + 0) * 64) = make_float2(a00 + bb, a01 + bb);
    bb = toF(b2[j0 + 1]); *(float2*)(base + (size_t)(j0 + 1) * 64) = make_float2(a10 + bb, a11 + bb);
    bb = toF(b2[j0 + 2]); *(float2*)(base + (size_t)(j0 + 2) * 64) = make_float2(a20 + bb, a21 + bb);
    bb = toF(b2[j0 + 3]); *(float2*)(base + (size_t)(j0 + 3) * 64) = make_float2(a30 + bb, a31 + bb);
}
__global__ __launch_bounds__(256)
void encproj(const void* feat, const void* W2, const void* b2, float* encT,
             const int* __restrict__ dtf)
{
    if (*dtf) encproj_body<unsigned short>((const unsigned short*)feat,
                  (const unsigned short*)W2, (const unsigned short*)b2, encT);
    else      encproj_body<float>((const float*)feat, (const float*)W2,
                  (const float*)b2, encT);
}

static void launch_legacy(void* const* d_in, void* d_out, void* d_ws, hipStream_t stream)
{
    const void* feat  = d_in[0];
    const void* emb   = d_in[3];
    const void* W1    = d_in[4];
    const void* b1    = d_in[5];
    const void* W2    = d_in[6];
    const void* b2    = d_in[7];
    const void* Va    = d_in[8];
    const void* bVa   = d_in[9];
    const void* Wh    = d_in[10];
    const void* bh    = d_in[11];
    const void* Wc    = d_in[12];
    const void* bc    = d_in[13];
    const void* Wg    = d_in[14];
    const void* bg    = d_in[15];
    const void* Wx    = d_in[16];
    const void* Whh   = d_in[17];
    const void* blstm = d_in[18];
    const void* Wout  = d_in[19];
    const void* bout  = d_in[20];

    float* ws         = (float*)d_ws;
    float* encT       = ws;
    float* meanT      = encT + 1048576;
    float* actT_h     = meanT + 40960;
    float* cT         = actT_h + 16384;
    float* hq_part    = cT + 16384;
    float* gate_part  = hq_part + 65536;
    float* gates_part = gate_part + 163840;
    float* ctxgT      = gates_part + 1179648;
    unsigned long long* amax = (unsigned long long*)(ctxgT + 40960);
    int* dtf          = (int*)(amax + 2560);
    float* k4part     = hq_part;

    detect_init<<<1, 256, 0, stream>>>((const unsigned short*)feat, dtf, amax);
    init_mean<<<160, 256, 0, stream>>>(feat, meanT, dtf);
    init_hc  <<<32, 256, 0, stream>>>(meanT, Wh, bh, Wc, bc, actT_h, cT, dtf);
    encproj  <<<512, 256, 0, stream>>>(feat, W2, b2, encT, dtf);

    SkArgs k1{};
    k1.r[0] = { W1,  nullptr, actT_h, hq_part,    512, 4, 128,  512, 0,  32 };
    k1.r[1] = { Wg,  nullptr, actT_h, gate_part, 1280, 4, 128, 1280, 0,  80 };
    k1.r[2] = { Whh, Wx,      actT_h, gates_part,2048, 8, 128, 2048, 1, 256 };
    k1.nReg = 3;
    SkArgs k3{};
    k3.r[0] = { Wx, nullptr, ctxgT,
                gates_part + (size_t)8 * 2048 * 32, 2048, 10, 128, 2048, 3, 320 };
    k3.nReg = 1;
    SkArgs k4{};
    k4.r[0] = { Wout, nullptr, actT_h, k4part, 10000, 4, 128, 10000, 0, 632 };
    k4.nReg = 1;

    for (int t = 0; t < 80; ++t) {
        skgemm     <<<368, 256,  0, stream>>>(k1, t, amax, emb, dtf);
        attn_kernel<<<32,  1024, 0, stream>>>(hq_part, gate_part, encT, feat,
                                              b1, Va, bVa, bg, ctxgT, d_out, t, dtf);
        skgemm     <<<320, 256,  0, stream>>>(k3, t, amax, emb, dtf);
        lstm_pw    <<<64,  256,  0, stream>>>(gates_part, blstm, cT, actT_h, d_out, t, dtf);
        skgemm     <<<632, 256,  0, stream>>>(k4, t, amax, emb, dtf);
        logits_fin <<<158, 256,  0, stream>>>(k4part, bout, d_out, amax, t, dtf);
    }
}

// ---------------------------------------------------------------------------
extern "C" void kernel_launch(void* const* d_in, const int* in_sizes, int n_in,
                              void* d_out, int out_size, void* d_ws, size_t ws_size,
                              hipStream_t stream)
{
    (void)in_sizes; (void)n_in; (void)out_size;

    if (ws_size >= WS_TOTAL_BYTES) {
        PArgs A;
        A.feat = d_in[0];  A.emb  = d_in[3];
        A.W1   = d_in[4];  A.b1   = d_in[5];
        A.W2   = d_in[6];  A.b2   = d_in[7];
        A.Va   = d_in[8];  A.bVa  = d_in[9];
        A.Wh   = d_in[10]; A.bh   = d_in[11];
        A.Wc   = d_in[12]; A.bc   = d_in[13];
        A.Wg   = d_in[14]; A.bg   = d_in[15];
        A.Wx   = d_in[16]; A.Whh  = d_in[17];
        A.blstm = d_in[18];
        A.Wout = d_in[19]; A.bout = d_in[20];
        A.dout = d_out;
        A.ws   = (float*)d_ws;

        void* kargs[1] = { (void*)&A };
        hipError_t err = hipLaunchCooperativeKernel(
            (const void*)decoder_persistent, dim3(256), dim3(1024), kargs, 0, stream);
        if (err == hipSuccess) return;
        (void)hipGetLastError();   // clear error state, fall back
    }
    launch_legacy(d_in, d_out, d_ws, stream);
}